// Round 1
// 7100.822 us; speedup vs baseline: 4.4766x; 4.4766x over previous
//
#include <hip/hip_runtime.h>
#include <hip/hip_bf16.h>
#include <math.h>

namespace {

using bf16 = __hip_bfloat16;
typedef __bf16 bf16x8 __attribute__((ext_vector_type(8)));
typedef float f32x4 __attribute__((ext_vector_type(4)));

constexpr int N_ = 65536, E_ = 262144, G_ = 1024, M_ = 64;
constexpr int D_ = 512, H_ = 8, C_ = 64, ED_ = 128, P_ = 1024, L_ = 5;
constexpr float SLOPE = 0.2f;
constexpr float EPSF = 1.1920929e-7f;   // finfo(float32).eps

constexpr int ECH = 8;                  // edge chunks
constexpr int ECHUNK = E_ / ECH;        // 32768 edges/chunk
constexpr int NCH = 8;                  // FFN row chunks
constexpr int NCHUNK = N_ / NCH;        // 8192 rows/chunk

__device__ inline float b2f(bf16 h) { return __bfloat162float(h); }
__device__ inline bf16 f2b(float f) { return __float2bfloat16(f); }
__device__ inline float us2f(unsigned short u) {
  return __uint_as_float((unsigned)u << 16);
}

// ---- ordered-uint encoding for float atomicMax ----
__device__ inline unsigned enc_f(float f) {
  unsigned u = __float_as_uint(f);
  return (u & 0x80000000u) ? ~u : (u | 0x80000000u);
}
__device__ inline float dec_f(unsigned e) {
  return (e & 0x80000000u) ? __uint_as_float(e & 0x7FFFFFFFu)
                           : __uint_as_float(~e);
}

// ---- async global->LDS, 16B/lane ----
typedef __attribute__((address_space(1))) void as1_void_t;
typedef __attribute__((address_space(3))) void as3_void_t;
__device__ inline void gload16(const void* g, void* l) {
  __builtin_amdgcn_global_load_lds((const as1_void_t*)g, (as3_void_t*)l, 16, 0,
                                   0);
}

// ============== MFMA bf16 GEMM: C[M,Nc] = A[M,K] @ Bt[Nc,K]^T + bias =========
// A row-major bf16, Bt = B^T row-major bf16. 128x128 tile, 4 waves (2x2),
// BK=64, global_load_lds staging with XOR-swizzled SOURCE (slot ^= row&7) so
// the ds_read_b128 fragment reads are bank-conflict-free (G21 both-sides rule:
// linear LDS dest + inverse-swizzled global src + swizzled read).
// M%128==0, Nc%128==0, K%64==0 (all shapes here satisfy this).
template <int EPI, int OBF>  // EPI: 0 none, 1 exact gelu; OBF: bf16 out?
__global__ __launch_bounds__(256) void mfma_gemm_k(
    const ushort* __restrict__ A, const ushort* __restrict__ Bt,
    const float* __restrict__ bias, void* __restrict__ Cv, int M, int K,
    int Nc) {
  __shared__ __align__(16) ushort As[128 * 64];  // [row][64], 128B rows
  __shared__ __align__(16) ushort Bs[128 * 64];
  const int tid = threadIdx.x;
  const int wave = tid >> 6, lane = tid & 63;
  const int m0 = blockIdx.x * 128, n0 = blockIdx.y * 128;
  const int wr = wave >> 1, wc = wave & 1;  // 2x2 wave grid, 64x64 each
  // staging: issue r covers rows [r*32, r*32+32); thread t -> row t/8, slot t&7
  const int srow = tid >> 3;
  const int skoff = (((tid & 7) ^ (srow & 7)) << 3);  // inverse-swizzled source
  const ushort* Ap = A + (size_t)(m0 + srow) * K + skoff;
  const ushort* Bp = Bt + (size_t)(n0 + srow) * K + skoff;
  char* AsB = (char*)As + wave * 1024;  // wave-uniform LDS base (+r*4096)
  char* BsB = (char*)Bs + wave * 1024;
  // fragment read: lane l -> row fr, k-group fg; swizzled slot = (ks*4+fg)^rx
  const int fr = lane & 15, fg = lane >> 4;
  const int rx = fr & 7;
  const int sA0 = ((fg) ^ rx) << 3;        // ks=0 slot offset (ushorts)
  const int sA1 = ((4 | fg) ^ rx) << 3;    // ks=1
  const ushort* Arow = As + (wr * 64 + fr) * 64;
  const ushort* Brow = Bs + (wc * 64 + fr) * 64;
  f32x4 acc[4][4];
#pragma unroll
  for (int i = 0; i < 4; ++i)
#pragma unroll
    for (int j = 0; j < 4; ++j) acc[i][j] = (f32x4){0.f, 0.f, 0.f, 0.f};

  for (int kt = 0; kt < K; kt += 64) {
#pragma unroll
    for (int r = 0; r < 4; ++r) {
      gload16(Ap + kt + (size_t)r * 32 * K, AsB + r * 4096);
      gload16(Bp + kt + (size_t)r * 32 * K, BsB + r * 4096);
    }
    __syncthreads();  // compiler drains vmcnt(0) before s_barrier
    bf16x8 af[4], bg[4];
#pragma unroll
    for (int i = 0; i < 4; ++i)
      af[i] = *(const bf16x8*)(Arow + i * 1024 + sA0);
#pragma unroll
    for (int j = 0; j < 4; ++j)
      bg[j] = *(const bf16x8*)(Brow + j * 1024 + sA0);
#pragma unroll
    for (int i = 0; i < 4; ++i)
#pragma unroll
      for (int j = 0; j < 4; ++j)
        acc[i][j] = __builtin_amdgcn_mfma_f32_16x16x32_bf16(af[i], bg[j],
                                                            acc[i][j], 0, 0, 0);
#pragma unroll
    for (int i = 0; i < 4; ++i)
      af[i] = *(const bf16x8*)(Arow + i * 1024 + sA1);
#pragma unroll
    for (int j = 0; j < 4; ++j)
      bg[j] = *(const bf16x8*)(Brow + j * 1024 + sA1);
#pragma unroll
    for (int i = 0; i < 4; ++i)
#pragma unroll
      for (int j = 0; j < 4; ++j)
        acc[i][j] = __builtin_amdgcn_mfma_f32_16x16x32_bf16(af[i], bg[j],
                                                            acc[i][j], 0, 0, 0);
    __syncthreads();
  }
  // epilogue: C/D frag mapping col=lane&15, row=(lane>>4)*4+reg (m89-verified)
  const int cb = n0 + wc * 64 + fr;
  float bv[4];
#pragma unroll
  for (int j = 0; j < 4; ++j) bv[j] = bias ? bias[cb + j * 16] : 0.f;
#pragma unroll
  for (int i = 0; i < 4; ++i) {
#pragma unroll
    for (int r = 0; r < 4; ++r) {
      int m = m0 + wr * 64 + i * 16 + fg * 4 + r;
      size_t rb = (size_t)m * Nc + cb;
#pragma unroll
      for (int j = 0; j < 4; ++j) {
        float c = acc[i][j][r] + bv[j];
        if (EPI == 1) c = 0.5f * c * (1.f + erff(c * 0.70710678118654752f));
        if (OBF)
          ((bf16*)Cv)[rb + j * 16] = f2b(c);
        else
          ((float*)Cv)[rb + j * 16] = c;
      }
    }
  }
}

// ---- one-time per layer: W[K][N] fp32 -> Wt[N][K] bf16 (B^T for the GEMM) ---
__global__ __launch_bounds__(256) void transpose_cvt_k(
    const float* __restrict__ W, bf16* __restrict__ Wt, int K, int N) {
  __shared__ float tile[32][33];
  int bn = blockIdx.x * 32, bk = blockIdx.y * 32;
  int tx = threadIdx.x, ty = threadIdx.y;  // (32,8)
#pragma unroll
  for (int i = ty; i < 32; i += 8) tile[i][tx] = W[(size_t)(bk + i) * N + bn + tx];
  __syncthreads();
#pragma unroll
  for (int i = ty; i < 32; i += 8)
    Wt[(size_t)(bn + i) * K + bk + tx] = f2b(tile[tx][i]);
}

// ========== legacy fp32 SIMT GEMM (kept only for the tiny fp32 head) =========
template <int EPI, typename TIN, typename TOUT>
__global__ __launch_bounds__(256) void gemm_bias_k(
    const TIN* __restrict__ A, const float* __restrict__ B,
    const float* __restrict__ bias, TOUT* __restrict__ C, int M, int K,
    int Nc) {
  __shared__ float As[64][17];
  __shared__ float Bs[16][68];
  const int tid = threadIdx.x;
  const int m0 = blockIdx.x * 64;
  const int n0 = blockIdx.y * 64;
  const int ty = tid >> 4, tx = tid & 15;
  const int lam = tid >> 2;
  const int lak = (tid & 3) << 2;
  const int lbk = tid >> 4;
  const int lbn = (tid & 15) << 2;
  const TIN* Aptr = A + (long)(m0 + lam) * K + lak;
  const float* Bptr = B + (long)lbk * Nc + n0 + lbn;
  float acc[4][4] = {};
  for (int kt = 0; kt < K; kt += 16) {
    float4 va = *(const float4*)(Aptr + kt);
    float4 vb = *(const float4*)(Bptr + (long)kt * Nc);
    __syncthreads();
    As[lam][lak + 0] = va.x; As[lam][lak + 1] = va.y;
    As[lam][lak + 2] = va.z; As[lam][lak + 3] = va.w;
    Bs[lbk][lbn + 0] = vb.x; Bs[lbk][lbn + 1] = vb.y;
    Bs[lbk][lbn + 2] = vb.z; Bs[lbk][lbn + 3] = vb.w;
    __syncthreads();
#pragma unroll
    for (int kk = 0; kk < 16; ++kk) {
      float a[4], b[4];
#pragma unroll
      for (int i = 0; i < 4; ++i) a[i] = As[ty * 4 + i][kk];
#pragma unroll
      for (int j = 0; j < 4; ++j) b[j] = Bs[kk][tx * 4 + j];
#pragma unroll
      for (int i = 0; i < 4; ++i)
#pragma unroll
        for (int j = 0; j < 4; ++j) acc[i][j] = fmaf(a[i], b[j], acc[i][j]);
    }
  }
#pragma unroll
  for (int i = 0; i < 4; ++i) {
    long row = (long)(m0 + ty * 4 + i) * Nc + n0;
#pragma unroll
    for (int j = 0; j < 4; ++j) {
      float c = acc[i][j] + (bias ? bias[n0 + tx * 4 + j] : 0.f);
      if (EPI == 1) c = 0.5f * c * (1.f + erff(c * 0.70710678118654752f));
      ((float*)C)[row + tx * 4 + j] = c;
    }
  }
}

// ================= encoders =================
__global__ __launch_bounds__(256) void encode_nodes_k(
    const int* __restrict__ nodeX, const float* __restrict__ atomEmb,
    bf16* __restrict__ x) {
  int n = blockIdx.x, tid = threadIdx.x;
  __shared__ int idx[9];
  if (tid < 9) idx[tid] = nodeX[n * 9 + tid];
  __syncthreads();
  for (int d = tid; d < D_; d += 256) {
    float s = 0.f;
#pragma unroll
    for (int k = 0; k < 9; ++k) s += atomEmb[(k * 119 + idx[k]) * D_ + d];
    x[(long)n * D_ + d] = f2b(s);
  }
}

__global__ __launch_bounds__(128) void encode_edges_k(
    const int* __restrict__ eai, const float* __restrict__ edgeEmb,
    bf16* __restrict__ eattr) {
  int e = blockIdx.x, tid = threadIdx.x;
  __shared__ int idx[3];
  if (tid < 3) idx[tid] = eai[e * 3 + tid];
  __syncthreads();
  float s = 0.f;
#pragma unroll
  for (int k = 0; k < 3; ++k) s += edgeEmb[(k * 22 + idx[k]) * ED_ + tid];
  eattr[(long)e * ED_ + tid] = f2b(s);
}

// ================= per-layer init =================
__global__ void init_md_k(unsigned* __restrict__ mx, float* __restrict__ denom) {
  int id = blockIdx.x * 256 + threadIdx.x;  // N*H
  mx[id] = 0x007FFFFFu;  // enc(-inf)
  denom[id] = 0.f;
}

// ================= GATv2 edge pipeline =================
// wave-per-edge: lane covers d = lane*8..+7 via uint4 (8 bf16) loads.
__global__ __launch_bounds__(256) void edge_logits_k(
    const ushort* __restrict__ xl, const ushort* __restrict__ xr,
    const ushort* __restrict__ ee, const float* __restrict__ att,
    const int* __restrict__ src, const int* __restrict__ dst,
    float* __restrict__ logits, unsigned* __restrict__ mx) {
  int e = blockIdx.x * 4 + (threadIdx.x >> 6);  // chunk-local edge
  int lane = threadIdx.x & 63;
  int s = src[e], t = dst[e];
  int d0 = lane * 8;
  uint4 a = *(const uint4*)(xl + (size_t)s * D_ + d0);
  uint4 b = *(const uint4*)(xr + (size_t)t * D_ + d0);
  uint4 c = *(const uint4*)(ee + (size_t)e * D_ + d0);
  float p = 0.f;
#pragma unroll
  for (int w = 0; w < 4; ++w) {
    unsigned ua = (&a.x)[w], ub = (&b.x)[w], uc = (&c.x)[w];
    float v0 = us2f((ushort)ua) + us2f((ushort)ub) + us2f((ushort)uc);
    float v1 = us2f((ushort)(ua >> 16)) + us2f((ushort)(ub >> 16)) +
               us2f((ushort)(uc >> 16));
    v0 = (v0 > 0.f) ? v0 : SLOPE * v0;
    v1 = (v1 > 0.f) ? v1 : SLOPE * v1;
    p = fmaf(v0, att[d0 + 2 * w], p);
    p = fmaf(v1, att[d0 + 2 * w + 1], p);
  }
#pragma unroll
  for (int o = 1; o < 8; o <<= 1) p += __shfl_xor(p, o);
  if ((lane & 7) == 0) {
    int h = lane >> 3;
    logits[(size_t)e * H_ + h] = p;
    atomicMax(&mx[(size_t)t * H_ + h], enc_f(p));
  }
}

__global__ __launch_bounds__(256) void edge_p_k(
    float* __restrict__ logits, const unsigned* __restrict__ mx,
    const int* __restrict__ dst, float* __restrict__ denom) {
  int id = blockIdx.x * 256 + threadIdx.x;  // E*H
  int e = id >> 3, h = id & 7;
  int t = dst[e];
  float p = expf(logits[id] - dec_f(mx[t * H_ + h]));
  logits[id] = p;
  atomicAdd(denom + t * H_ + h, p);
}

__global__ __launch_bounds__(256) void edge_alpha_k(
    float* __restrict__ logits, const float* __restrict__ denom,
    const int* __restrict__ dst) {
  int id = blockIdx.x * 256 + threadIdx.x;  // E*H
  int e = id >> 3, h = id & 7;
  logits[id] /= denom[dst[e] * H_ + h];
}

// ---- fused CSR-gather + gb + residual + rmsnorm (replaces atomic scatter) ---
__global__ __launch_bounds__(256) void gat_aggr_norm_k(
    bf16* __restrict__ x, const bf16* __restrict__ xl,
    const float* __restrict__ alpha, const int* __restrict__ ptr,
    const int* __restrict__ eid, const int* __restrict__ src,
    const float* __restrict__ gb, const float* __restrict__ w) {
  int n = blockIdx.x, tid = threadIdx.x;
  long base = (long)n * D_;
  float acc0 = gb[tid], acc1 = gb[tid + 256];
  int h0 = tid >> 6, h1 = h0 + 4;
  int beg = ptr[n], end = ptr[n + 1];
  for (int i = beg; i < end; ++i) {
    int e = eid[i];
    int s = src[e];
    float a0 = alpha[(long)e * H_ + h0];
    float a1 = alpha[(long)e * H_ + h1];
    long sb = (long)s * D_;
    acc0 += b2f(xl[sb + tid]) * a0;
    acc1 += b2f(xl[sb + tid + 256]) * a1;
  }
  float v0 = b2f(x[base + tid]) + acc0;
  float v1 = b2f(x[base + tid + 256]) + acc1;
  float ss = v0 * v0 + v1 * v1;
#pragma unroll
  for (int o = 32; o > 0; o >>= 1) ss += __shfl_xor(ss, o);
  __shared__ float wsum[4];
  if ((tid & 63) == 0) wsum[tid >> 6] = ss;
  __syncthreads();
  float tot = wsum[0] + wsum[1] + wsum[2] + wsum[3];
  float scale = rsqrtf(tot * (1.0f / D_) + EPSF);
  x[base + tid] = f2b(v0 * scale * w[tid]);
  x[base + tid + 256] = f2b(v1 * scale * w[tid + 256]);
}

// ================= rmsnorm(x + xa) for the FFN residual =================
__global__ __launch_bounds__(256) void rmsnorm_res_k(
    bf16* __restrict__ x, const float* __restrict__ xa,
    const float* __restrict__ w) {
  int n = blockIdx.x, tid = threadIdx.x;
  long base = (long)n * D_;
  float v0 = b2f(x[base + tid]) + xa[base + tid];
  float v1 = b2f(x[base + tid + 256]) + xa[base + tid + 256];
  float ss = v0 * v0 + v1 * v1;
#pragma unroll
  for (int o = 32; o > 0; o >>= 1) ss += __shfl_xor(ss, o);
  __shared__ float wsum[4];
  if ((tid & 63) == 0) wsum[tid >> 6] = ss;
  __syncthreads();
  float tot = wsum[0] + wsum[1] + wsum[2] + wsum[3];
  float scale = rsqrtf(tot * (1.0f / D_) + EPSF);
  x[base + tid] = f2b(v0 * scale * w[tid]);
  x[base + tid + 256] = f2b(v1 * scale * w[tid + 256]);
}

// ================= bookkeeping =================
__global__ void zero_int_k(int* __restrict__ p) {
  p[blockIdx.x * 256 + threadIdx.x] = 0;
}
__global__ void count_k(const int* __restrict__ key, int* __restrict__ counts) {
  int id = blockIdx.x * 256 + threadIdx.x;
  atomicAdd(&counts[key[id]], 1);
}
__global__ void copy_int_k(const int* __restrict__ in, int* __restrict__ out) {
  int id = blockIdx.x * 256 + threadIdx.x;
  out[id] = in[id];
}
__global__ void fill_csr_k(const int* __restrict__ dst,
                           int* __restrict__ cursor, int* __restrict__ eid) {
  int e = blockIdx.x * 256 + threadIdx.x;
  int pos = atomicAdd(&cursor[dst[e]], 1);
  eid[pos] = e;
}
// exclusive scan over N=65536 ints, single block of 1024 threads
__global__ __launch_bounds__(1024) void scanN_k(const int* __restrict__ cnt,
                                                int* __restrict__ ptr) {
  __shared__ int sums[1024];
  int t = threadIdx.x;
  int base = t * 64;
  int s = 0;
  for (int i = 0; i < 64; ++i) s += cnt[base + i];
  sums[t] = s;
  __syncthreads();
  for (int off = 1; off < 1024; off <<= 1) {
    int v = (t >= off) ? sums[t - off] : 0;
    __syncthreads();
    sums[t] += v;
    __syncthreads();
  }
  int run = (t > 0) ? sums[t - 1] : 0;
  for (int i = 0; i < 64; ++i) {
    ptr[base + i] = run;
    run += cnt[base + i];
  }
  if (t == 1023) ptr[N_] = run;
}
__global__ void scan_k(const int* __restrict__ counts, int* __restrict__ starts) {
  __shared__ int buf[G_];
  int t = threadIdx.x;
  int c = counts[t];
  buf[t] = c;
  __syncthreads();
  for (int off = 1; off < G_; off <<= 1) {
    int v = (t >= off) ? buf[t - off] : 0;
    __syncthreads();
    buf[t] += v;
    __syncthreads();
  }
  starts[t] = buf[t] - c;  // exclusive
}

// ================= attention pooling (z is bf16) =================
__global__ __launch_bounds__(256) void pool_k(
    const bf16* __restrict__ z, const float* __restrict__ avW,
    const float* __restrict__ avb, const int* __restrict__ counts,
    const int* __restrict__ starts, float* __restrict__ hg) {
  int g = blockIdx.x, tid = threadIdx.x;
  int cnt = counts[g], st = starts[g];
  __shared__ float aL[M_];
  int wave = tid >> 6, lane = tid & 63;
  for (int m = wave; m < M_; m += 4) {
    float s = 0.f;
    if (m < cnt) {
      const bf16* row = z + (long)(st + m) * D_;
      for (int c = lane; c < D_; c += 64) s += b2f(row[c]) * avW[c];
    }
#pragma unroll
    for (int o = 32; o > 0; o >>= 1) s += __shfl_xor(s, o);
    if (lane == 0) aL[m] = s;
  }
  __syncthreads();
  if (tid < 64) {
    float v = (tid < cnt) ? aL[tid] + avb[0] : -__builtin_inff();
    float mxv = v;
#pragma unroll
    for (int o = 32; o > 0; o >>= 1) mxv = fmaxf(mxv, __shfl_xor(mxv, o));
    float p = (tid < cnt) ? expf(v - mxv) : 0.f;
    float sm = p;
#pragma unroll
    for (int o = 32; o > 0; o >>= 1) sm += __shfl_xor(sm, o);
    aL[tid] = p / sm;
  }
  __syncthreads();
  for (int d = tid; d < D_; d += 256) {
    float acc = 0.f;
    for (int m = 0; m < cnt; ++m) acc += b2f(z[(long)(st + m) * D_ + d]) * aL[m];
    hg[(long)g * D_ + d] = acc;
  }
}

__global__ __launch_bounds__(256) void rms_relu_k(
    const float* __restrict__ in, const float* __restrict__ w,
    float* __restrict__ out) {
  int g = blockIdx.x, tid = threadIdx.x;
  long base = (long)g * P_;
  float v[4], ss = 0.f;
#pragma unroll
  for (int k = 0; k < 4; ++k) {
    v[k] = in[base + tid + k * 256];
    ss += v[k] * v[k];
  }
#pragma unroll
  for (int o = 32; o > 0; o >>= 1) ss += __shfl_xor(ss, o);
  __shared__ float wsum[4];
  if ((tid & 63) == 0) wsum[tid >> 6] = ss;
  __syncthreads();
  float tot = wsum[0] + wsum[1] + wsum[2] + wsum[3];
  float scale = rsqrtf(tot * (1.0f / P_) + EPSF);
#pragma unroll
  for (int k = 0; k < 4; ++k) {
    float c = v[k] * scale * w[tid + k * 256];
    out[base + tid + k * 256] = fmaxf(c, 0.f);
  }
}

// ================= final outputs =================
__global__ __launch_bounds__(256) void write_dense_k(
    const bf16* __restrict__ x, const int* __restrict__ counts,
    const int* __restrict__ starts, float* __restrict__ out1) {
  long id = (long)blockIdx.x * 256 + threadIdx.x;  // G*M*D
  int g = (int)(id >> 15);
  int rem = (int)(id & 32767);
  int m = rem >> 9, d = rem & 511;
  float v = 0.f;
  if (m < counts[g]) v = b2f(x[(long)(starts[g] + m) * D_ + d]);
  out1[id] = v;
}
__global__ void write_mask_k(const int* __restrict__ counts,
                             float* __restrict__ out2) {
  int id = blockIdx.x * 256 + threadIdx.x;  // G*M
  out2[id] = ((id & 63) < counts[id >> 6]) ? 1.f : 0.f;
}

}  // namespace

extern "C" void kernel_launch(void* const* d_in, const int* in_sizes, int n_in,
                              void* d_out, int out_size, void* d_ws,
                              size_t ws_size, hipStream_t stream) {
  const int* node_x = (const int*)d_in[0];
  const int* edge_attr_idx = (const int*)d_in[1];
  const int* edge_index = (const int*)d_in[2];
  const int* batch = (const int*)d_in[3];
  const float* atom_emb = (const float*)d_in[4];
  const float* edge_emb = (const float*)d_in[5];
  const float* Wl = (const float*)d_in[6];
  const float* bl = (const float*)d_in[7];
  const float* Wr = (const float*)d_in[8];
  const float* br = (const float*)d_in[9];
  const float* We = (const float*)d_in[10];
  const float* att = (const float*)d_in[11];
  const float* gb = (const float*)d_in[12];
  const float* n1w = (const float*)d_in[13];
  const float* f1w = (const float*)d_in[14];
  const float* f1b = (const float*)d_in[15];
  const float* f2w = (const float*)d_in[16];
  const float* f2b = (const float*)d_in[17];
  const float* n2w = (const float*)d_in[18];
  const float* gapW = (const float*)d_in[19];
  const float* gapb = (const float*)d_in[20];
  const float* avW = (const float*)d_in[21];
  const float* avb = (const float*)d_in[22];
  const float* p1W = (const float*)d_in[23];
  const float* p1b = (const float*)d_in[24];
  const float* pnw = (const float*)d_in[25];
  const float* p2W = (const float*)d_in[26];
  const float* p2b = (const float*)d_in[27];
  const int* src = edge_index;
  const int* dst = edge_index + E_;

  // ---- workspace layout (identical footprint to previous version) ----
  char* ws = (char*)d_ws;
  bf16* x = (bf16*)ws;                                   // N*D bf16
  bf16* xl = x + (long)N_ * D_;                          // N*D bf16
  bf16* xr = xl + (long)N_ * D_;                         // N*D bf16
  bf16* eebuf = xr + (long)N_ * D_;   // max(ECHUNK*D, NCHUNK*4D) bf16 (alias)
  bf16* echunk = eebuf + (long)ECHUNK * D_;              // ECHUNK*ED bf16
  float* logits = (float*)(echunk + (long)ECHUNK * ED_); // E*H fp32
  unsigned* mx = (unsigned*)(logits + (long)E_ * H_);    // N*H
  float* denom = (float*)(mx + (long)N_ * H_);           // N*H
  int* counts = (int*)(denom + (long)N_ * H_);           // G
  int* starts = counts + G_;                             // G
  float* hg = (float*)(starts + G_);                     // G*D fp32
  float* tmpP = hg + (long)G_ * D_;                      // G*P fp32
  float* hp = tmpP + (long)G_ * P_;                      // G*P fp32
  bf16* hid = eebuf;                                     // NCHUNK*4D alias

  // per-layer bf16 transposed weights, aliased on tmpP+hp (dead during layers)
  bf16* wsc = (bf16*)tmpP;  // 8.39 MB available, 5.37 MB used
  bf16* Wl_b = wsc;
  bf16* Wr_b = Wl_b + 512 * 512;
  bf16* We_b = Wr_b + 512 * 512;        // [512][128]
  bf16* f1w_b = We_b + 512 * 128;       // [2048][512]
  bf16* f2w_b = f1w_b + 2048 * 512;     // [512][2048]

  float* out0 = (float*)d_out;                 // [G,P]
  float* out1 = out0 + (long)G_ * P_;          // [G,M,D]
  float* out2 = out1 + (long)G_ * M_ * D_;     // [G,M]
  float* xa = out1;  // FFN residual accumulator aliases out1 (dead at end)

  // dst-CSR lives in out0 (written only at the very end of the launch)
  int* csr_eid = (int*)out0;        // E
  int* csr_ptr = csr_eid + E_;      // N+1
  int* cursor = csr_ptr + N_ + 1;   // N

  encode_nodes_k<<<N_, 256, 0, stream>>>(node_x, atom_emb, x);

  // ---- build dst-CSR once (dst is layer-invariant) ----
  zero_int_k<<<N_ / 256, 256, 0, stream>>>(cursor);
  count_k<<<E_ / 256, 256, 0, stream>>>(dst, cursor);
  scanN_k<<<1, 1024, 0, stream>>>(cursor, csr_ptr);
  copy_int_k<<<N_ / 256, 256, 0, stream>>>(csr_ptr, cursor);
  fill_csr_k<<<E_ / 256, 256, 0, stream>>>(dst, cursor, csr_eid);

  for (int l = 0; l < L_; ++l) {
    const float* Wl_l = Wl + (long)l * D_ * D_;
    const float* bl_l = bl + (long)l * D_;
    const float* Wr_l = Wr + (long)l * D_ * D_;
    const float* br_l = br + (long)l * D_;
    const float* We_l = We + (long)l * ED_ * D_;
    const float* att_l = att + (long)l * H_ * C_;
    const float* gb_l = gb + (long)l * D_;
    const float* n1w_l = n1w + (long)l * D_;
    const float* f1w_l = f1w + (long)l * D_ * 4 * D_;
    const float* f1b_l = f1b + (long)l * 4 * D_;
    const float* f2w_l = f2w + (long)l * 4 * D_ * D_;
    const float* f2b_l = f2b + (long)l * D_;
    const float* n2w_l = n2w + (long)l * D_;

    // weights -> bf16 B^T
    transpose_cvt_k<<<dim3(16, 16), dim3(32, 8), 0, stream>>>(Wl_l, Wl_b, 512, 512);
    transpose_cvt_k<<<dim3(16, 16), dim3(32, 8), 0, stream>>>(Wr_l, Wr_b, 512, 512);
    transpose_cvt_k<<<dim3(16, 4), dim3(32, 8), 0, stream>>>(We_l, We_b, 128, 512);
    transpose_cvt_k<<<dim3(64, 16), dim3(32, 8), 0, stream>>>(f1w_l, f1w_b, 512, 2048);
    transpose_cvt_k<<<dim3(16, 64), dim3(32, 8), 0, stream>>>(f2w_l, f2w_b, 2048, 512);

    mfma_gemm_k<0, 1><<<dim3(N_ / 128, D_ / 128), 256, 0, stream>>>(
        (const ushort*)x, (const ushort*)Wl_b, bl_l, xl, N_, D_, D_);
    mfma_gemm_k<0, 1><<<dim3(N_ / 128, D_ / 128), 256, 0, stream>>>(
        (const ushort*)x, (const ushort*)Wr_b, br_l, xr, N_, D_, D_);
    init_md_k<<<(N_ * H_) / 256, 256, 0, stream>>>(mx, denom);

    for (int ec = 0; ec < ECH; ++ec) {
      long ebase = (long)ec * ECHUNK;
      encode_edges_k<<<ECHUNK, 128, 0, stream>>>(
          edge_attr_idx + ebase * 3, edge_emb, echunk);
      mfma_gemm_k<0, 1><<<dim3(ECHUNK / 128, D_ / 128), 256, 0, stream>>>(
          (const ushort*)echunk, (const ushort*)We_b, nullptr, eebuf, ECHUNK,
          ED_, D_);
      edge_logits_k<<<ECHUNK / 4, 256, 0, stream>>>(
          (const ushort*)xl, (const ushort*)xr, (const ushort*)eebuf, att_l,
          src + ebase, dst + ebase, logits + ebase * H_, mx);
    }
    edge_p_k<<<(E_ * H_) / 256, 256, 0, stream>>>(logits, mx, dst, denom);
    edge_alpha_k<<<(E_ * H_) / 256, 256, 0, stream>>>(logits, denom, dst);
    gat_aggr_norm_k<<<N_, 256, 0, stream>>>(x, xl, logits, csr_ptr, csr_eid,
                                            src, gb_l, n1w_l);

    for (int nc = 0; nc < NCH; ++nc) {
      long nbase = (long)nc * NCHUNK;
      mfma_gemm_k<1, 1><<<dim3(NCHUNK / 128, (4 * D_) / 128), 256, 0, stream>>>(
          (const ushort*)(x + nbase * D_), (const ushort*)f1w_b, f1b_l, hid,
          NCHUNK, D_, 4 * D_);
      mfma_gemm_k<0, 0><<<dim3(NCHUNK / 128, D_ / 128), 256, 0, stream>>>(
          (const ushort*)hid, (const ushort*)f2w_b, f2b_l, xa + nbase * D_,
          NCHUNK, 4 * D_, D_);
    }
    rmsnorm_res_k<<<N_, 256, 0, stream>>>(x, xa, n2w_l);
  }

  // batch bookkeeping
  zero_int_k<<<G_ / 256, 256, 0, stream>>>(counts);
  count_k<<<N_ / 256, 256, 0, stream>>>(batch, counts);
  scan_k<<<1, G_, 0, stream>>>(counts, starts);

  // pooling head: z into xl; gapW bf16^T into echunk (free now)
  bf16* gapW_b = echunk;
  transpose_cvt_k<<<dim3(16, 16), dim3(32, 8), 0, stream>>>(gapW, gapW_b, 512, 512);
  mfma_gemm_k<0, 1><<<dim3(N_ / 128, D_ / 128), 256, 0, stream>>>(
      (const ushort*)x, (const ushort*)gapW_b, gapb, xl, N_, D_, D_);
  pool_k<<<G_, 256, 0, stream>>>(xl, avW, avb, counts, starts, hg);
  gemm_bias_k<0, float, float><<<dim3(G_ / 64, P_ / 64), 256, 0, stream>>>(
      hg, p1W, p1b, tmpP, G_, D_, P_);
  rms_relu_k<<<G_, 256, 0, stream>>>(tmpP, pnw, hp);
  gemm_bias_k<0, float, float><<<dim3(G_ / 64, P_ / 64), 256, 0, stream>>>(
      hp, p2W, p2b, out0, G_, P_, P_);

  write_dense_k<<<(int)(((long)G_ * M_ * D_) / 256), 256, 0, stream>>>(
      x, counts, starts, out1);
  write_mask_k<<<(G_ * M_) / 256, 256, 0, stream>>>(counts, out2);
}

// Round 2
// 6366.747 us; speedup vs baseline: 4.9928x; 1.1153x over previous
//
#include <hip/hip_runtime.h>
#include <hip/hip_bf16.h>
#include <math.h>

namespace {

using bf16 = __hip_bfloat16;
typedef __bf16 bf16x8 __attribute__((ext_vector_type(8)));
typedef float f32x4 __attribute__((ext_vector_type(4)));

constexpr int N_ = 65536, E_ = 262144, G_ = 1024, M_ = 64;
constexpr int D_ = 512, H_ = 8, C_ = 64, ED_ = 128, P_ = 1024, L_ = 5;
constexpr float SLOPE = 0.2f;
constexpr float EPSF = 1.1920929e-7f;   // finfo(float32).eps

constexpr int ECH = 8;                  // edge chunks
constexpr int ECHUNK = E_ / ECH;        // 32768 edges/chunk
constexpr int NCH = 2;                  // FFN row chunks (hid aliases xl+xr)
constexpr int NCHUNK = N_ / NCH;        // 32768 rows/chunk

__device__ inline float b2f(bf16 h) { return __bfloat162float(h); }
__device__ inline bf16 f2b(float f) { return __float2bfloat16(f); }
__device__ inline float us2f(unsigned short u) {
  return __uint_as_float((unsigned)u << 16);
}

// ---- async global->LDS, 16B/lane ----
typedef __attribute__((address_space(1))) void as1_void_t;
typedef __attribute__((address_space(3))) void as3_void_t;
__device__ inline void gload16(const void* g, void* l) {
  __builtin_amdgcn_global_load_lds((const as1_void_t*)g, (as3_void_t*)l, 16, 0,
                                   0);
}

// ============== MFMA bf16 GEMM: C[M,Nc] = A[M,K] @ Bt[Nc,K]^T + bias =========
// A row-major bf16, Bt = B^T row-major bf16. 128x128 tile, 4 waves (2x2),
// BK=64, global_load_lds staging with XOR-swizzled SOURCE (slot ^= row&7) so
// the ds_read_b128 fragment reads are bank-conflict-free (G21 both-sides rule:
// linear LDS dest + inverse-swizzled global src + swizzled read).
// M%128==0, Nc%128==0, K%64==0 (all shapes here satisfy this).
template <int EPI, int OBF>  // EPI: 0 none, 1 exact gelu; OBF: bf16 out?
__global__ __launch_bounds__(256) void mfma_gemm_k(
    const ushort* __restrict__ A, const ushort* __restrict__ Bt,
    const float* __restrict__ bias, void* __restrict__ Cv, int M, int K,
    int Nc) {
  __shared__ __align__(16) ushort As[128 * 64];  // [row][64], 128B rows
  __shared__ __align__(16) ushort Bs[128 * 64];
  const int tid = threadIdx.x;
  const int wave = tid >> 6, lane = tid & 63;
  const int m0 = blockIdx.x * 128, n0 = blockIdx.y * 128;
  const int wr = wave >> 1, wc = wave & 1;  // 2x2 wave grid, 64x64 each
  // staging: issue r covers rows [r*32, r*32+32); thread t -> row t/8, slot t&7
  const int srow = tid >> 3;
  const int skoff = (((tid & 7) ^ (srow & 7)) << 3);  // inverse-swizzled source
  const ushort* Ap = A + (size_t)(m0 + srow) * K + skoff;
  const ushort* Bp = Bt + (size_t)(n0 + srow) * K + skoff;
  char* AsB = (char*)As + wave * 1024;  // wave-uniform LDS base (+r*4096)
  char* BsB = (char*)Bs + wave * 1024;
  // fragment read: lane l -> row fr, k-group fg; swizzled slot = (ks*4+fg)^rx
  const int fr = lane & 15, fg = lane >> 4;
  const int rx = fr & 7;
  const int sA0 = ((fg) ^ rx) << 3;        // ks=0 slot offset (ushorts)
  const int sA1 = ((4 | fg) ^ rx) << 3;    // ks=1
  const ushort* Arow = As + (wr * 64 + fr) * 64;
  const ushort* Brow = Bs + (wc * 64 + fr) * 64;
  f32x4 acc[4][4];
#pragma unroll
  for (int i = 0; i < 4; ++i)
#pragma unroll
    for (int j = 0; j < 4; ++j) acc[i][j] = (f32x4){0.f, 0.f, 0.f, 0.f};

  for (int kt = 0; kt < K; kt += 64) {
#pragma unroll
    for (int r = 0; r < 4; ++r) {
      gload16(Ap + kt + (size_t)r * 32 * K, AsB + r * 4096);
      gload16(Bp + kt + (size_t)r * 32 * K, BsB + r * 4096);
    }
    __syncthreads();  // compiler drains vmcnt(0) before s_barrier
    bf16x8 af[4], bg[4];
#pragma unroll
    for (int i = 0; i < 4; ++i)
      af[i] = *(const bf16x8*)(Arow + i * 1024 + sA0);
#pragma unroll
    for (int j = 0; j < 4; ++j)
      bg[j] = *(const bf16x8*)(Brow + j * 1024 + sA0);
#pragma unroll
    for (int i = 0; i < 4; ++i)
#pragma unroll
      for (int j = 0; j < 4; ++j)
        acc[i][j] = __builtin_amdgcn_mfma_f32_16x16x32_bf16(af[i], bg[j],
                                                            acc[i][j], 0, 0, 0);
#pragma unroll
    for (int i = 0; i < 4; ++i)
      af[i] = *(const bf16x8*)(Arow + i * 1024 + sA1);
#pragma unroll
    for (int j = 0; j < 4; ++j)
      bg[j] = *(const bf16x8*)(Brow + j * 1024 + sA1);
#pragma unroll
    for (int i = 0; i < 4; ++i)
#pragma unroll
      for (int j = 0; j < 4; ++j)
        acc[i][j] = __builtin_amdgcn_mfma_f32_16x16x32_bf16(af[i], bg[j],
                                                            acc[i][j], 0, 0, 0);
    __syncthreads();
  }
  // epilogue: C/D frag mapping col=lane&15, row=(lane>>4)*4+reg (m89-verified)
  const int cb = n0 + wc * 64 + fr;
  float bv[4];
#pragma unroll
  for (int j = 0; j < 4; ++j) bv[j] = bias ? bias[cb + j * 16] : 0.f;
#pragma unroll
  for (int i = 0; i < 4; ++i) {
#pragma unroll
    for (int r = 0; r < 4; ++r) {
      int m = m0 + wr * 64 + i * 16 + fg * 4 + r;
      size_t rb = (size_t)m * Nc + cb;
#pragma unroll
      for (int j = 0; j < 4; ++j) {
        float c = acc[i][j][r] + bv[j];
        if (EPI == 1) c = 0.5f * c * (1.f + erff(c * 0.70710678118654752f));
        if (OBF)
          ((bf16*)Cv)[rb + j * 16] = f2b(c);
        else
          ((float*)Cv)[rb + j * 16] = c;
      }
    }
  }
}

// ---- one-time per layer: W[K][N] fp32 -> Wt[N][K] bf16 (B^T for the GEMM) ---
__global__ __launch_bounds__(256) void transpose_cvt_k(
    const float* __restrict__ W, bf16* __restrict__ Wt, int K, int N) {
  __shared__ float tile[32][33];
  int bn = blockIdx.x * 32, bk = blockIdx.y * 32;
  int tx = threadIdx.x, ty = threadIdx.y;  // (32,8)
#pragma unroll
  for (int i = ty; i < 32; i += 8) tile[i][tx] = W[(size_t)(bk + i) * N + bn + tx];
  __syncthreads();
#pragma unroll
  for (int i = ty; i < 32; i += 8)
    Wt[(size_t)(bn + i) * K + bk + tx] = f2b(tile[tx][i]);
}

// ========== legacy fp32 SIMT GEMM (kept only for the tiny fp32 head) =========
template <int EPI, typename TIN, typename TOUT>
__global__ __launch_bounds__(256) void gemm_bias_k(
    const TIN* __restrict__ A, const float* __restrict__ B,
    const float* __restrict__ bias, TOUT* __restrict__ C, int M, int K,
    int Nc) {
  __shared__ float As[64][17];
  __shared__ float Bs[16][68];
  const int tid = threadIdx.x;
  const int m0 = blockIdx.x * 64;
  const int n0 = blockIdx.y * 64;
  const int ty = tid >> 4, tx = tid & 15;
  const int lam = tid >> 2;
  const int lak = (tid & 3) << 2;
  const int lbk = tid >> 4;
  const int lbn = (tid & 15) << 2;
  const TIN* Aptr = A + (long)(m0 + lam) * K + lak;
  const float* Bptr = B + (long)lbk * Nc + n0 + lbn;
  float acc[4][4] = {};
  for (int kt = 0; kt < K; kt += 16) {
    float4 va = *(const float4*)(Aptr + kt);
    float4 vb = *(const float4*)(Bptr + (long)kt * Nc);
    __syncthreads();
    As[lam][lak + 0] = va.x; As[lam][lak + 1] = va.y;
    As[lam][lak + 2] = va.z; As[lam][lak + 3] = va.w;
    Bs[lbk][lbn + 0] = vb.x; Bs[lbk][lbn + 1] = vb.y;
    Bs[lbk][lbn + 2] = vb.z; Bs[lbk][lbn + 3] = vb.w;
    __syncthreads();
#pragma unroll
    for (int kk = 0; kk < 16; ++kk) {
      float a[4], b[4];
#pragma unroll
      for (int i = 0; i < 4; ++i) a[i] = As[ty * 4 + i][kk];
#pragma unroll
      for (int j = 0; j < 4; ++j) b[j] = Bs[kk][tx * 4 + j];
#pragma unroll
      for (int i = 0; i < 4; ++i)
#pragma unroll
        for (int j = 0; j < 4; ++j) acc[i][j] = fmaf(a[i], b[j], acc[i][j]);
    }
  }
#pragma unroll
  for (int i = 0; i < 4; ++i) {
    long row = (long)(m0 + ty * 4 + i) * Nc + n0;
#pragma unroll
    for (int j = 0; j < 4; ++j) {
      float c = acc[i][j] + (bias ? bias[n0 + tx * 4 + j] : 0.f);
      if (EPI == 1) c = 0.5f * c * (1.f + erff(c * 0.70710678118654752f));
      ((float*)C)[row + tx * 4 + j] = c;
    }
  }
}

// ================= encoders =================
__global__ __launch_bounds__(256) void encode_nodes_k(
    const int* __restrict__ nodeX, const float* __restrict__ atomEmb,
    bf16* __restrict__ x) {
  int n = blockIdx.x, tid = threadIdx.x;
  __shared__ int idx[9];
  if (tid < 9) idx[tid] = nodeX[n * 9 + tid];
  __syncthreads();
  for (int d = tid; d < D_; d += 256) {
    float s = 0.f;
#pragma unroll
    for (int k = 0; k < 9; ++k) s += atomEmb[(k * 119 + idx[k]) * D_ + d];
    x[(long)n * D_ + d] = f2b(s);
  }
}

__global__ __launch_bounds__(128) void encode_edges_k(
    const int* __restrict__ eai, const float* __restrict__ edgeEmb,
    bf16* __restrict__ eattr) {
  int e = blockIdx.x, tid = threadIdx.x;
  __shared__ int idx[3];
  if (tid < 3) idx[tid] = eai[e * 3 + tid];
  __syncthreads();
  float s = 0.f;
#pragma unroll
  for (int k = 0; k < 3; ++k) s += edgeEmb[(k * 22 + idx[k]) * ED_ + tid];
  eattr[(long)e * ED_ + tid] = f2b(s);
}

// ================= GATv2 edge pipeline =================
// wave-per-edge: lane covers d = lane*8..+7 via uint4 (8 bf16) loads.
// Writes RAW logits only; segment softmax is fused into gat_aggr_norm_k.
__global__ __launch_bounds__(256) void edge_logits_k(
    const ushort* __restrict__ xl, const ushort* __restrict__ xr,
    const ushort* __restrict__ ee, const float* __restrict__ att,
    const int* __restrict__ src, const int* __restrict__ dst,
    float* __restrict__ logits) {
  int e = blockIdx.x * 4 + (threadIdx.x >> 6);  // chunk-local edge
  int lane = threadIdx.x & 63;
  int s = src[e], t = dst[e];
  (void)t;
  int d0 = lane * 8;
  uint4 a = *(const uint4*)(xl + (size_t)s * D_ + d0);
  uint4 b = *(const uint4*)(xr + (size_t)t * D_ + d0);
  uint4 c = *(const uint4*)(ee + (size_t)e * D_ + d0);
  float p = 0.f;
#pragma unroll
  for (int w = 0; w < 4; ++w) {
    unsigned ua = (&a.x)[w], ub = (&b.x)[w], uc = (&c.x)[w];
    float v0 = us2f((ushort)ua) + us2f((ushort)ub) + us2f((ushort)uc);
    float v1 = us2f((ushort)(ua >> 16)) + us2f((ushort)(ub >> 16)) +
               us2f((ushort)(uc >> 16));
    v0 = (v0 > 0.f) ? v0 : SLOPE * v0;
    v1 = (v1 > 0.f) ? v1 : SLOPE * v1;
    p = fmaf(v0, att[d0 + 2 * w], p);
    p = fmaf(v1, att[d0 + 2 * w + 1], p);
  }
#pragma unroll
  for (int o = 1; o < 8; o <<= 1) p += __shfl_xor(p, o);
  if ((lane & 7) == 0) {
    int h = lane >> 3;
    logits[(size_t)e * H_ + h] = p;
  }
}

// ---- fused CSR-gather + segment-softmax + gb + residual + rmsnorm ----------
// result_d = (sum_e p_e * xl[src_e,d]) / (sum_e p_e) + gb_d, p = exp(l - max)
__global__ __launch_bounds__(256) void gat_aggr_norm_k(
    bf16* __restrict__ x, const bf16* __restrict__ xl,
    const float* __restrict__ logits, const int* __restrict__ ptr,
    const int* __restrict__ eid, const int* __restrict__ src,
    const float* __restrict__ gb, const float* __restrict__ w) {
  int n = blockIdx.x, tid = threadIdx.x;
  long base = (long)n * D_;
  int h0 = tid >> 6, h1 = h0 + 4;
  int beg = ptr[n], end = ptr[n + 1];
  // pass 1: per-head max over in-edges (broadcast loads within the lane group)
  float m0 = -__builtin_inff(), m1 = -__builtin_inff();
  for (int i = beg; i < end; ++i) {
    int e = eid[i];
    m0 = fmaxf(m0, logits[(long)e * H_ + h0]);
    m1 = fmaxf(m1, logits[(long)e * H_ + h1]);
  }
  // pass 2: weighted gather with unnormalized p; divide once at the end
  float s0 = 0.f, s1 = 0.f, d0 = 0.f, d1 = 0.f;
  for (int i = beg; i < end; ++i) {
    int e = eid[i];
    int sv = src[e];
    float p0 = expf(logits[(long)e * H_ + h0] - m0);
    float p1 = expf(logits[(long)e * H_ + h1] - m1);
    d0 += p0;
    d1 += p1;
    long sb = (long)sv * D_;
    s0 += b2f(xl[sb + tid]) * p0;
    s1 += b2f(xl[sb + tid + 256]) * p1;
  }
  float inv0 = (end > beg) ? 1.f / d0 : 0.f;
  float inv1 = (end > beg) ? 1.f / d1 : 0.f;
  float v0 = b2f(x[base + tid]) + s0 * inv0 + gb[tid];
  float v1 = b2f(x[base + tid + 256]) + s1 * inv1 + gb[tid + 256];
  float ss = v0 * v0 + v1 * v1;
#pragma unroll
  for (int o = 32; o > 0; o >>= 1) ss += __shfl_xor(ss, o);
  __shared__ float wsum[4];
  if ((tid & 63) == 0) wsum[tid >> 6] = ss;
  __syncthreads();
  float tot = wsum[0] + wsum[1] + wsum[2] + wsum[3];
  float scale = rsqrtf(tot * (1.0f / D_) + EPSF);
  x[base + tid] = f2b(v0 * scale * w[tid]);
  x[base + tid + 256] = f2b(v1 * scale * w[tid + 256]);
}

// ================= rmsnorm(x + xa) for the FFN residual =================
__global__ __launch_bounds__(256) void rmsnorm_res_k(
    bf16* __restrict__ x, const float* __restrict__ xa,
    const float* __restrict__ w) {
  int n = blockIdx.x, tid = threadIdx.x;
  long base = (long)n * D_;
  float v0 = b2f(x[base + tid]) + xa[base + tid];
  float v1 = b2f(x[base + tid + 256]) + xa[base + tid + 256];
  float ss = v0 * v0 + v1 * v1;
#pragma unroll
  for (int o = 32; o > 0; o >>= 1) ss += __shfl_xor(ss, o);
  __shared__ float wsum[4];
  if ((tid & 63) == 0) wsum[tid >> 6] = ss;
  __syncthreads();
  float tot = wsum[0] + wsum[1] + wsum[2] + wsum[3];
  float scale = rsqrtf(tot * (1.0f / D_) + EPSF);
  x[base + tid] = f2b(v0 * scale * w[tid]);
  x[base + tid + 256] = f2b(v1 * scale * w[tid + 256]);
}

// ================= bookkeeping =================
__global__ void zero_int_k(int* __restrict__ p) {
  p[blockIdx.x * 256 + threadIdx.x] = 0;
}
__global__ void count_k(const int* __restrict__ key, int* __restrict__ counts) {
  int id = blockIdx.x * 256 + threadIdx.x;
  atomicAdd(&counts[key[id]], 1);
}
__global__ void copy_int_k(const int* __restrict__ in, int* __restrict__ out) {
  int id = blockIdx.x * 256 + threadIdx.x;
  out[id] = in[id];
}
__global__ void fill_csr_k(const int* __restrict__ dst,
                           int* __restrict__ cursor, int* __restrict__ eid) {
  int e = blockIdx.x * 256 + threadIdx.x;
  int pos = atomicAdd(&cursor[dst[e]], 1);
  eid[pos] = e;
}
// exclusive scan over N=65536 ints, single block of 1024 threads
__global__ __launch_bounds__(1024) void scanN_k(const int* __restrict__ cnt,
                                                int* __restrict__ ptr) {
  __shared__ int sums[1024];
  int t = threadIdx.x;
  int base = t * 64;
  int s = 0;
  for (int i = 0; i < 64; ++i) s += cnt[base + i];
  sums[t] = s;
  __syncthreads();
  for (int off = 1; off < 1024; off <<= 1) {
    int v = (t >= off) ? sums[t - off] : 0;
    __syncthreads();
    sums[t] += v;
    __syncthreads();
  }
  int run = (t > 0) ? sums[t - 1] : 0;
  for (int i = 0; i < 64; ++i) {
    ptr[base + i] = run;
    run += cnt[base + i];
  }
  if (t == 1023) ptr[N_] = run;
}
__global__ void scan_k(const int* __restrict__ counts, int* __restrict__ starts) {
  __shared__ int buf[G_];
  int t = threadIdx.x;
  int c = counts[t];
  buf[t] = c;
  __syncthreads();
  for (int off = 1; off < G_; off <<= 1) {
    int v = (t >= off) ? buf[t - off] : 0;
    __syncthreads();
    buf[t] += v;
    __syncthreads();
  }
  starts[t] = buf[t] - c;  // exclusive
}

// ================= attention pooling (z is bf16) =================
__global__ __launch_bounds__(256) void pool_k(
    const bf16* __restrict__ z, const float* __restrict__ avW,
    const float* __restrict__ avb, const int* __restrict__ counts,
    const int* __restrict__ starts, float* __restrict__ hg) {
  int g = blockIdx.x, tid = threadIdx.x;
  int cnt = counts[g], st = starts[g];
  __shared__ float aL[M_];
  int wave = tid >> 6, lane = tid & 63;
  for (int m = wave; m < M_; m += 4) {
    float s = 0.f;
    if (m < cnt) {
      const bf16* row = z + (long)(st + m) * D_;
      for (int c = lane; c < D_; c += 64) s += b2f(row[c]) * avW[c];
    }
#pragma unroll
    for (int o = 32; o > 0; o >>= 1) s += __shfl_xor(s, o);
    if (lane == 0) aL[m] = s;
  }
  __syncthreads();
  if (tid < 64) {
    float v = (tid < cnt) ? aL[tid] + avb[0] : -__builtin_inff();
    float mxv = v;
#pragma unroll
    for (int o = 32; o > 0; o >>= 1) mxv = fmaxf(mxv, __shfl_xor(mxv, o));
    float p = (tid < cnt) ? expf(v - mxv) : 0.f;
    float sm = p;
#pragma unroll
    for (int o = 32; o > 0; o >>= 1) sm += __shfl_xor(sm, o);
    aL[tid] = p / sm;
  }
  __syncthreads();
  for (int d = tid; d < D_; d += 256) {
    float acc = 0.f;
    for (int m = 0; m < cnt; ++m) acc += b2f(z[(long)(st + m) * D_ + d]) * aL[m];
    hg[(long)g * D_ + d] = acc;
  }
}

__global__ __launch_bounds__(256) void rms_relu_k(
    const float* __restrict__ in, const float* __restrict__ w,
    float* __restrict__ out) {
  int g = blockIdx.x, tid = threadIdx.x;
  long base = (long)g * P_;
  float v[4], ss = 0.f;
#pragma unroll
  for (int k = 0; k < 4; ++k) {
    v[k] = in[base + tid + k * 256];
    ss += v[k] * v[k];
  }
#pragma unroll
  for (int o = 32; o > 0; o >>= 1) ss += __shfl_xor(ss, o);
  __shared__ float wsum[4];
  if ((tid & 63) == 0) wsum[tid >> 6] = ss;
  __syncthreads();
  float tot = wsum[0] + wsum[1] + wsum[2] + wsum[3];
  float scale = rsqrtf(tot * (1.0f / P_) + EPSF);
#pragma unroll
  for (int k = 0; k < 4; ++k) {
    float c = v[k] * scale * w[tid + k * 256];
    out[base + tid + k * 256] = fmaxf(c, 0.f);
  }
}

// ================= final outputs =================
__global__ __launch_bounds__(256) void write_dense_k(
    const bf16* __restrict__ x, const int* __restrict__ counts,
    const int* __restrict__ starts, float* __restrict__ out1) {
  long id = (long)blockIdx.x * 256 + threadIdx.x;  // G*M*D
  int g = (int)(id >> 15);
  int rem = (int)(id & 32767);
  int m = rem >> 9, d = rem & 511;
  float v = 0.f;
  if (m < counts[g]) v = b2f(x[(long)(starts[g] + m) * D_ + d]);
  out1[id] = v;
}
__global__ void write_mask_k(const int* __restrict__ counts,
                             float* __restrict__ out2) {
  int id = blockIdx.x * 256 + threadIdx.x;  // G*M
  out2[id] = ((id & 63) < counts[id >> 6]) ? 1.f : 0.f;
}

}  // namespace

extern "C" void kernel_launch(void* const* d_in, const int* in_sizes, int n_in,
                              void* d_out, int out_size, void* d_ws,
                              size_t ws_size, hipStream_t stream) {
  const int* node_x = (const int*)d_in[0];
  const int* edge_attr_idx = (const int*)d_in[1];
  const int* edge_index = (const int*)d_in[2];
  const int* batch = (const int*)d_in[3];
  const float* atom_emb = (const float*)d_in[4];
  const float* edge_emb = (const float*)d_in[5];
  const float* Wl = (const float*)d_in[6];
  const float* bl = (const float*)d_in[7];
  const float* Wr = (const float*)d_in[8];
  const float* br = (const float*)d_in[9];
  const float* We = (const float*)d_in[10];
  const float* att = (const float*)d_in[11];
  const float* gb = (const float*)d_in[12];
  const float* n1w = (const float*)d_in[13];
  const float* f1w = (const float*)d_in[14];
  const float* f1b = (const float*)d_in[15];
  const float* f2w = (const float*)d_in[16];
  const float* f2b = (const float*)d_in[17];
  const float* n2w = (const float*)d_in[18];
  const float* gapW = (const float*)d_in[19];
  const float* gapb = (const float*)d_in[20];
  const float* avW = (const float*)d_in[21];
  const float* avb = (const float*)d_in[22];
  const float* p1W = (const float*)d_in[23];
  const float* p1b = (const float*)d_in[24];
  const float* pnw = (const float*)d_in[25];
  const float* p2W = (const float*)d_in[26];
  const float* p2b = (const float*)d_in[27];
  const int* src = edge_index;
  const int* dst = edge_index + E_;

  // ---- workspace layout (identical footprint to previous version) ----
  char* ws = (char*)d_ws;
  bf16* x = (bf16*)ws;                                   // N*D bf16
  bf16* xl = x + (long)N_ * D_;                          // N*D bf16
  bf16* xr = xl + (long)N_ * D_;                         // N*D bf16
  bf16* eebuf = xr + (long)N_ * D_;                      // ECHUNK*D bf16
  bf16* echunk = eebuf + (long)ECHUNK * D_;              // ECHUNK*ED bf16
  float* logits = (float*)(echunk + (long)ECHUNK * ED_); // E*H fp32
  unsigned* mx = (unsigned*)(logits + (long)E_ * H_);    // N*H (unused now)
  float* denom = (float*)(mx + (long)N_ * H_);           // N*H (unused now)
  int* counts = (int*)(denom + (long)N_ * H_);           // G
  int* starts = counts + G_;                             // G
  float* hg = (float*)(starts + G_);                     // G*D fp32
  float* tmpP = hg + (long)G_ * D_;                      // G*P fp32
  float* hp = tmpP + (long)G_ * P_;                      // G*P fp32
  // FFN hidden buffer aliases xl+xr (both dead during FFN phase):
  // NCHUNK*4D bf16 = 32768*2048*2 B = 134.2 MB = |xl| + |xr| exactly.
  bf16* hid = xl;

  // per-layer bf16 transposed weights, aliased on tmpP+hp (dead during layers)
  bf16* wsc = (bf16*)tmpP;  // 8.39 MB available, 5.37 MB used
  bf16* Wl_b = wsc;
  bf16* Wr_b = Wl_b + 512 * 512;
  bf16* We_b = Wr_b + 512 * 512;        // [512][128]
  bf16* f1w_b = We_b + 512 * 128;       // [2048][512]
  bf16* f2w_b = f1w_b + 2048 * 512;     // [512][2048]

  float* out0 = (float*)d_out;                 // [G,P]
  float* out1 = out0 + (long)G_ * P_;          // [G,M,D]
  float* out2 = out1 + (long)G_ * M_ * D_;     // [G,M]
  float* xa = out1;  // FFN residual accumulator aliases out1 (dead at end)

  // dst-CSR lives in out0 (written only at the very end of the launch)
  int* csr_eid = (int*)out0;        // E
  int* csr_ptr = csr_eid + E_;      // N+1
  int* cursor = csr_ptr + N_ + 1;   // N

  encode_nodes_k<<<N_, 256, 0, stream>>>(node_x, atom_emb, x);

  // ---- build dst-CSR once (dst is layer-invariant) ----
  zero_int_k<<<N_ / 256, 256, 0, stream>>>(cursor);
  count_k<<<E_ / 256, 256, 0, stream>>>(dst, cursor);
  scanN_k<<<1, 1024, 0, stream>>>(cursor, csr_ptr);
  copy_int_k<<<N_ / 256, 256, 0, stream>>>(csr_ptr, cursor);
  fill_csr_k<<<E_ / 256, 256, 0, stream>>>(dst, cursor, csr_eid);

  for (int l = 0; l < L_; ++l) {
    const float* Wl_l = Wl + (long)l * D_ * D_;
    const float* bl_l = bl + (long)l * D_;
    const float* Wr_l = Wr + (long)l * D_ * D_;
    const float* br_l = br + (long)l * D_;
    const float* We_l = We + (long)l * ED_ * D_;
    const float* att_l = att + (long)l * H_ * C_;
    const float* gb_l = gb + (long)l * D_;
    const float* n1w_l = n1w + (long)l * D_;
    const float* f1w_l = f1w + (long)l * D_ * 4 * D_;
    const float* f1b_l = f1b + (long)l * 4 * D_;
    const float* f2w_l = f2w + (long)l * 4 * D_ * D_;
    const float* f2b_l = f2b + (long)l * D_;
    const float* n2w_l = n2w + (long)l * D_;

    // weights -> bf16 B^T
    transpose_cvt_k<<<dim3(16, 16), dim3(32, 8), 0, stream>>>(Wl_l, Wl_b, 512, 512);
    transpose_cvt_k<<<dim3(16, 16), dim3(32, 8), 0, stream>>>(Wr_l, Wr_b, 512, 512);
    transpose_cvt_k<<<dim3(16, 4), dim3(32, 8), 0, stream>>>(We_l, We_b, 128, 512);
    transpose_cvt_k<<<dim3(64, 16), dim3(32, 8), 0, stream>>>(f1w_l, f1w_b, 512, 2048);
    transpose_cvt_k<<<dim3(16, 64), dim3(32, 8), 0, stream>>>(f2w_l, f2w_b, 2048, 512);

    mfma_gemm_k<0, 1><<<dim3(N_ / 128, D_ / 128), 256, 0, stream>>>(
        (const ushort*)x, (const ushort*)Wl_b, bl_l, xl, N_, D_, D_);
    mfma_gemm_k<0, 1><<<dim3(N_ / 128, D_ / 128), 256, 0, stream>>>(
        (const ushort*)x, (const ushort*)Wr_b, br_l, xr, N_, D_, D_);

    for (int ec = 0; ec < ECH; ++ec) {
      long ebase = (long)ec * ECHUNK;
      encode_edges_k<<<ECHUNK, 128, 0, stream>>>(
          edge_attr_idx + ebase * 3, edge_emb, echunk);
      mfma_gemm_k<0, 1><<<dim3(ECHUNK / 128, D_ / 128), 256, 0, stream>>>(
          (const ushort*)echunk, (const ushort*)We_b, nullptr, eebuf, ECHUNK,
          ED_, D_);
      edge_logits_k<<<ECHUNK / 4, 256, 0, stream>>>(
          (const ushort*)xl, (const ushort*)xr, (const ushort*)eebuf, att_l,
          src + ebase, dst + ebase, logits + ebase * H_);
    }
    gat_aggr_norm_k<<<N_, 256, 0, stream>>>(x, xl, logits, csr_ptr, csr_eid,
                                            src, gb_l, n1w_l);

    for (int nc = 0; nc < NCH; ++nc) {
      long nbase = (long)nc * NCHUNK;
      mfma_gemm_k<1, 1><<<dim3(NCHUNK / 128, (4 * D_) / 128), 256, 0, stream>>>(
          (const ushort*)(x + nbase * D_), (const ushort*)f1w_b, f1b_l, hid,
          NCHUNK, D_, 4 * D_);
      mfma_gemm_k<0, 0><<<dim3(NCHUNK / 128, D_ / 128), 256, 0, stream>>>(
          (const ushort*)hid, (const ushort*)f2w_b, f2b_l, xa + nbase * D_,
          NCHUNK, 4 * D_, D_);
    }
    rmsnorm_res_k<<<N_, 256, 0, stream>>>(x, xa, n2w_l);
  }

  // batch bookkeeping
  zero_int_k<<<G_ / 256, 256, 0, stream>>>(counts);
  count_k<<<N_ / 256, 256, 0, stream>>>(batch, counts);
  scan_k<<<1, G_, 0, stream>>>(counts, starts);

  // pooling head: z into xl; gapW bf16^T into echunk (free now)
  bf16* gapW_b = echunk;
  transpose_cvt_k<<<dim3(16, 16), dim3(32, 8), 0, stream>>>(gapW, gapW_b, 512, 512);
  mfma_gemm_k<0, 1><<<dim3(N_ / 128, D_ / 128), 256, 0, stream>>>(
      (const ushort*)x, (const ushort*)gapW_b, gapb, xl, N_, D_, D_);
  pool_k<<<G_, 256, 0, stream>>>(xl, avW, avb, counts, starts, hg);
  gemm_bias_k<0, float, float><<<dim3(G_ / 64, P_ / 64), 256, 0, stream>>>(
      hg, p1W, p1b, tmpP, G_, D_, P_);
  rms_relu_k<<<G_, 256, 0, stream>>>(tmpP, pnw, hp);
  gemm_bias_k<0, float, float><<<dim3(G_ / 64, P_ / 64), 256, 0, stream>>>(
      hp, p2W, p2b, out0, G_, P_, P_);

  write_dense_k<<<(int)(((long)G_ * M_ * D_) / 256), 256, 0, stream>>>(
      x, counts, starts, out1);
  write_mask_k<<<(G_ * M_) / 256, 256, 0, stream>>>(counts, out2);
}

// Round 3
// 5131.102 us; speedup vs baseline: 6.1951x; 1.2408x over previous
//
#include <hip/hip_runtime.h>
#include <hip/hip_bf16.h>
#include <math.h>

namespace {

using bf16 = __hip_bfloat16;
typedef __bf16 bf16x8 __attribute__((ext_vector_type(8)));
typedef float f32x4 __attribute__((ext_vector_type(4)));

constexpr int N_ = 65536, E_ = 262144, G_ = 1024, M_ = 64;
constexpr int D_ = 512, H_ = 8, C_ = 64, ED_ = 128, P_ = 1024, L_ = 5;
constexpr float SLOPE = 0.2f;
constexpr float EPSF = 1.1920929e-7f;   // finfo(float32).eps

constexpr int NCH = 2;                  // FFN row chunks (hid aliases xl+xr)
constexpr int NCHUNK = N_ / NCH;        // 32768 rows/chunk

constexpr int TV = 22;                  // edge vocab per slot
constexpr int TK = TV * TV * TV;        // 10648 distinct edge types
constexpr int TKP = 10752;              // padded to %128

__device__ inline float b2f(bf16 h) { return __bfloat162float(h); }
__device__ inline bf16 f2b(float f) { return __float2bfloat16(f); }
__device__ inline float us2f(unsigned short u) {
  return __uint_as_float((unsigned)u << 16);
}
__device__ inline unsigned short f2us(float f) {
  bf16 b = __float2bfloat16(f);
  return *(unsigned short*)&b;
}

// ---- async global->LDS, 16B/lane ----
typedef __attribute__((address_space(1))) void as1_void_t;
typedef __attribute__((address_space(3))) void as3_void_t;
__device__ inline void gload16(const void* g, void* l) {
  __builtin_amdgcn_global_load_lds((const as1_void_t*)g, (as3_void_t*)l, 16, 0,
                                   0);
}

// ============== MFMA bf16 GEMM: C[M,Nc] = A[M,K] @ Bt[Nc,K]^T + bias =========
// A row-major bf16, Bt = B^T row-major bf16. 128x128 tile, 4 waves (2x2),
// BK=64, global_load_lds staging with XOR-swizzled SOURCE (slot ^= row&7) so
// the ds_read_b128 fragment reads are bank-conflict-free (G21 both-sides rule:
// linear LDS dest + inverse-swizzled global src + swizzled read).
// M%128==0, Nc%128==0, K%64==0 (all shapes here satisfy this).
template <int EPI, int OBF>  // EPI: 0 none, 1 exact gelu; OBF: bf16 out?
__global__ __launch_bounds__(256) void mfma_gemm_k(
    const ushort* __restrict__ A, const ushort* __restrict__ Bt,
    const float* __restrict__ bias, void* __restrict__ Cv, int M, int K,
    int Nc) {
  __shared__ __align__(16) ushort As[128 * 64];  // [row][64], 128B rows
  __shared__ __align__(16) ushort Bs[128 * 64];
  const int tid = threadIdx.x;
  const int wave = tid >> 6, lane = tid & 63;
  const int m0 = blockIdx.x * 128, n0 = blockIdx.y * 128;
  const int wr = wave >> 1, wc = wave & 1;  // 2x2 wave grid, 64x64 each
  // staging: issue r covers rows [r*32, r*32+32); thread t -> row t/8, slot t&7
  const int srow = tid >> 3;
  const int skoff = (((tid & 7) ^ (srow & 7)) << 3);  // inverse-swizzled source
  const ushort* Ap = A + (size_t)(m0 + srow) * K + skoff;
  const ushort* Bp = Bt + (size_t)(n0 + srow) * K + skoff;
  char* AsB = (char*)As + wave * 1024;  // wave-uniform LDS base (+r*4096)
  char* BsB = (char*)Bs + wave * 1024;
  // fragment read: lane l -> row fr, k-group fg; swizzled slot = (ks*4+fg)^rx
  const int fr = lane & 15, fg = lane >> 4;
  const int rx = fr & 7;
  const int sA0 = ((fg) ^ rx) << 3;        // ks=0 slot offset (ushorts)
  const int sA1 = ((4 | fg) ^ rx) << 3;    // ks=1
  const ushort* Arow = As + (wr * 64 + fr) * 64;
  const ushort* Brow = Bs + (wc * 64 + fr) * 64;
  f32x4 acc[4][4];
#pragma unroll
  for (int i = 0; i < 4; ++i)
#pragma unroll
    for (int j = 0; j < 4; ++j) acc[i][j] = (f32x4){0.f, 0.f, 0.f, 0.f};

  for (int kt = 0; kt < K; kt += 64) {
#pragma unroll
    for (int r = 0; r < 4; ++r) {
      gload16(Ap + kt + (size_t)r * 32 * K, AsB + r * 4096);
      gload16(Bp + kt + (size_t)r * 32 * K, BsB + r * 4096);
    }
    __syncthreads();  // compiler drains vmcnt(0) before s_barrier
    bf16x8 af[4], bg[4];
#pragma unroll
    for (int i = 0; i < 4; ++i)
      af[i] = *(const bf16x8*)(Arow + i * 1024 + sA0);
#pragma unroll
    for (int j = 0; j < 4; ++j)
      bg[j] = *(const bf16x8*)(Brow + j * 1024 + sA0);
#pragma unroll
    for (int i = 0; i < 4; ++i)
#pragma unroll
      for (int j = 0; j < 4; ++j)
        acc[i][j] = __builtin_amdgcn_mfma_f32_16x16x32_bf16(af[i], bg[j],
                                                            acc[i][j], 0, 0, 0);
#pragma unroll
    for (int i = 0; i < 4; ++i)
      af[i] = *(const bf16x8*)(Arow + i * 1024 + sA1);
#pragma unroll
    for (int j = 0; j < 4; ++j)
      bg[j] = *(const bf16x8*)(Brow + j * 1024 + sA1);
#pragma unroll
    for (int i = 0; i < 4; ++i)
#pragma unroll
      for (int j = 0; j < 4; ++j)
        acc[i][j] = __builtin_amdgcn_mfma_f32_16x16x32_bf16(af[i], bg[j],
                                                            acc[i][j], 0, 0, 0);
    __syncthreads();
  }
  // epilogue: C/D frag mapping col=lane&15, row=(lane>>4)*4+reg (m89-verified)
  const int cb = n0 + wc * 64 + fr;
  float bv[4];
#pragma unroll
  for (int j = 0; j < 4; ++j) bv[j] = bias ? bias[cb + j * 16] : 0.f;
#pragma unroll
  for (int i = 0; i < 4; ++i) {
#pragma unroll
    for (int r = 0; r < 4; ++r) {
      int m = m0 + wr * 64 + i * 16 + fg * 4 + r;
      size_t rb = (size_t)m * Nc + cb;
#pragma unroll
      for (int j = 0; j < 4; ++j) {
        float c = acc[i][j][r] + bv[j];
        if (EPI == 1) c = 0.5f * c * (1.f + erff(c * 0.70710678118654752f));
        if (OBF)
          ((bf16*)Cv)[rb + j * 16] = f2b(c);
        else
          ((float*)Cv)[rb + j * 16] = c;
      }
    }
  }
}

// ---- one-time per layer: W[K][N] fp32 -> Wt[N][K] bf16 (B^T for the GEMM) ---
__global__ __launch_bounds__(256) void transpose_cvt_k(
    const float* __restrict__ W, bf16* __restrict__ Wt, int K, int N) {
  __shared__ float tile[32][33];
  int bn = blockIdx.x * 32, bk = blockIdx.y * 32;
  int tx = threadIdx.x, ty = threadIdx.y;  // (32,8)
#pragma unroll
  for (int i = ty; i < 32; i += 8) tile[i][tx] = W[(size_t)(bk + i) * N + bn + tx];
  __syncthreads();
#pragma unroll
  for (int i = ty; i < 32; i += 8)
    Wt[(size_t)(bn + i) * K + bk + tx] = f2b(tile[tx][i]);
}

// ========== legacy fp32 SIMT GEMM (kept only for the tiny fp32 head) =========
template <int EPI, typename TIN, typename TOUT>
__global__ __launch_bounds__(256) void gemm_bias_k(
    const TIN* __restrict__ A, const float* __restrict__ B,
    const float* __restrict__ bias, TOUT* __restrict__ C, int M, int K,
    int Nc) {
  __shared__ float As[64][17];
  __shared__ float Bs[16][68];
  const int tid = threadIdx.x;
  const int m0 = blockIdx.x * 64;
  const int n0 = blockIdx.y * 64;
  const int ty = tid >> 4, tx = tid & 15;
  const int lam = tid >> 2;
  const int lak = (tid & 3) << 2;
  const int lbk = tid >> 4;
  const int lbn = (tid & 15) << 2;
  const TIN* Aptr = A + (long)(m0 + lam) * K + lak;
  const float* Bptr = B + (long)lbk * Nc + n0 + lbn;
  float acc[4][4] = {};
  for (int kt = 0; kt < K; kt += 16) {
    float4 va = *(const float4*)(Aptr + kt);
    float4 vb = *(const float4*)(Bptr + (long)kt * Nc);
    __syncthreads();
    As[lam][lak + 0] = va.x; As[lam][lak + 1] = va.y;
    As[lam][lak + 2] = va.z; As[lam][lak + 3] = va.w;
    Bs[lbk][lbn + 0] = vb.x; Bs[lbk][lbn + 1] = vb.y;
    Bs[lbk][lbn + 2] = vb.z; Bs[lbk][lbn + 3] = vb.w;
    __syncthreads();
#pragma unroll
    for (int kk = 0; kk < 16; ++kk) {
      float a[4], b[4];
#pragma unroll
      for (int i = 0; i < 4; ++i) a[i] = As[ty * 4 + i][kk];
#pragma unroll
      for (int j = 0; j < 4; ++j) b[j] = Bs[kk][tx * 4 + j];
#pragma unroll
      for (int i = 0; i < 4; ++i)
#pragma unroll
        for (int j = 0; j < 4; ++j) acc[i][j] = fmaf(a[i], b[j], acc[i][j]);
    }
  }
#pragma unroll
  for (int i = 0; i < 4; ++i) {
    long row = (long)(m0 + ty * 4 + i) * Nc + n0;
#pragma unroll
    for (int j = 0; j < 4; ++j) {
      float c = acc[i][j] + (bias ? bias[n0 + tx * 4 + j] : 0.f);
      if (EPI == 1) c = 0.5f * c * (1.f + erff(c * 0.70710678118654752f));
      ((float*)C)[row + tx * 4 + j] = c;
    }
  }
}

// ================= encoders =================
__global__ __launch_bounds__(256) void encode_nodes_k(
    const int* __restrict__ nodeX, const float* __restrict__ atomEmb,
    bf16* __restrict__ x) {
  int n = blockIdx.x, tid = threadIdx.x;
  __shared__ int idx[9];
  if (tid < 9) idx[tid] = nodeX[n * 9 + tid];
  __syncthreads();
  for (int d = tid; d < D_; d += 256) {
    float s = 0.f;
#pragma unroll
    for (int k = 0; k < 9; ++k) s += atomEmb[(k * 119 + idx[k]) * D_ + d];
    x[(long)n * D_ + d] = f2b(s);
  }
}

// edge-type key per edge: key = i0*TV^2 + i1*TV + i2  (layer-invariant)
__global__ __launch_bounds__(256) void build_keys_k(
    const int* __restrict__ eai, int* __restrict__ keys) {
  int e = blockIdx.x * 256 + threadIdx.x;
  keys[e] = eai[e * 3] * (TV * TV) + eai[e * 3 + 1] * TV + eai[e * 3 + 2];
}

// eattr table: one row per distinct (i0,i1,i2); rows >= TK zeroed (GEMM pad)
__global__ __launch_bounds__(128) void build_eattr_tab_k(
    const float* __restrict__ edgeEmb, bf16* __restrict__ tab) {
  int r = blockIdx.x, d = threadIdx.x;
  float s = 0.f;
  if (r < TK) {
    int k0 = r / (TV * TV), k1 = (r / TV) % TV, k2 = r % TV;
    s = edgeEmb[(0 * TV + k0) * ED_ + d] + edgeEmb[(1 * TV + k1) * ED_ + d] +
        edgeEmb[(2 * TV + k2) * ED_ + d];
  }
  tab[(size_t)r * ED_ + d] = f2b(s);
}

// ================= GATv2 edge pipeline =================
// wave-per-edge: lane covers d = lane*8..+7 via uint4 (8 bf16) loads.
// ee comes from the per-type table via keys. Writes RAW logits only.
__global__ __launch_bounds__(256) void edge_logits_k(
    const ushort* __restrict__ xl, const ushort* __restrict__ xr,
    const ushort* __restrict__ ee_tab, const int* __restrict__ keys,
    const float* __restrict__ att, const int* __restrict__ src,
    const int* __restrict__ dst, float* __restrict__ logits) {
  int e = blockIdx.x * 4 + (threadIdx.x >> 6);
  int lane = threadIdx.x & 63;
  int s = src[e], t = dst[e], key = keys[e];
  int d0 = lane * 8;
  uint4 a = *(const uint4*)(xl + (size_t)s * D_ + d0);
  uint4 b = *(const uint4*)(xr + (size_t)t * D_ + d0);
  uint4 c = *(const uint4*)(ee_tab + (size_t)key * D_ + d0);
  float p = 0.f;
#pragma unroll
  for (int w = 0; w < 4; ++w) {
    unsigned ua = (&a.x)[w], ub = (&b.x)[w], uc = (&c.x)[w];
    float v0 = us2f((ushort)ua) + us2f((ushort)ub) + us2f((ushort)uc);
    float v1 = us2f((ushort)(ua >> 16)) + us2f((ushort)(ub >> 16)) +
               us2f((ushort)(uc >> 16));
    v0 = (v0 > 0.f) ? v0 : SLOPE * v0;
    v1 = (v1 > 0.f) ? v1 : SLOPE * v1;
    p = fmaf(v0, att[d0 + 2 * w], p);
    p = fmaf(v1, att[d0 + 2 * w + 1], p);
  }
#pragma unroll
  for (int o = 1; o < 8; o <<= 1) p += __shfl_xor(p, o);
  if ((lane & 7) == 0) {
    logits[(size_t)e * H_ + (lane >> 3)] = p;
  }
}

// ---- fused CSR-gather + segment-softmax + gb + residual + rmsnorm ----------
// Phase A: stash eid/src in LDS; 8 threads compute per-head max/p/denom.
// Phase B: all threads gather-FMA with LDS-broadcast p; 2 bf16 per thread.
__global__ __launch_bounds__(256) void gat_aggr_norm_k(
    bf16* __restrict__ x, const bf16* __restrict__ xl,
    const float* __restrict__ logits, const int* __restrict__ ptr,
    const int* __restrict__ eid, const int* __restrict__ src,
    const float* __restrict__ gb, const float* __restrict__ w) {
  constexpr int PCAP = 40;  // in-degree cache cap (avg deg = 4)
  __shared__ int se_e[PCAP], se_s[PCAP];
  __shared__ float pa[PCAP * 8];  // unnormalized p per (edge, head)
  __shared__ float mh[8], invden[8];
  __shared__ float wsum[4];
  int n = blockIdx.x, tid = threadIdx.x;
  int beg = ptr[n], deg = ptr[n + 1] - beg;
  if (tid < PCAP && tid < deg) {
    int ed = eid[beg + tid];
    se_e[tid] = ed;
    se_s[tid] = src[ed];
  }
  __syncthreads();
  if (tid < 8) {
    int h = tid;
    float m = -__builtin_inff();
    for (int i = 0; i < deg; ++i) {
      int e = (i < PCAP) ? se_e[i] : eid[beg + i];
      m = fmaxf(m, logits[(size_t)e * H_ + h]);
    }
    float den = 0.f;
    for (int i = 0; i < deg; ++i) {
      int e = (i < PCAP) ? se_e[i] : eid[beg + i];
      float p = expf(logits[(size_t)e * H_ + h] - m);
      den += p;
      if (i < PCAP) pa[i * 8 + h] = p;
    }
    mh[h] = m;
    invden[h] = (deg > 0) ? 1.f / den : 0.f;
  }
  __syncthreads();
  int h = tid >> 5;  // d0 = tid*2 -> head = tid/32
  float acc0 = 0.f, acc1 = 0.f;
  for (int i = 0; i < deg; ++i) {
    float p;
    int s;
    if (i < PCAP) {
      p = pa[i * 8 + h];
      s = se_s[i];
    } else {
      int e = eid[beg + i];
      s = src[e];
      p = expf(logits[(size_t)e * H_ + h] - mh[h]);
    }
    unsigned u = *(const unsigned*)((const ushort*)xl + (size_t)s * D_ + tid * 2);
    acc0 = fmaf(us2f((ushort)u), p, acc0);
    acc1 = fmaf(us2f((ushort)(u >> 16)), p, acc1);
  }
  float inv = invden[h];
  long base = (long)n * D_;
  unsigned xu = *(const unsigned*)((const ushort*)x + base + tid * 2);
  float v0 = us2f((ushort)xu) + acc0 * inv + gb[tid * 2];
  float v1 = us2f((ushort)(xu >> 16)) + acc1 * inv + gb[tid * 2 + 1];
  float ss = v0 * v0 + v1 * v1;
#pragma unroll
  for (int o = 32; o > 0; o >>= 1) ss += __shfl_xor(ss, o);
  if ((tid & 63) == 0) wsum[tid >> 6] = ss;
  __syncthreads();
  float tot = wsum[0] + wsum[1] + wsum[2] + wsum[3];
  float scale = rsqrtf(tot * (1.0f / D_) + EPSF);
  unsigned outw = (unsigned)f2us(v0 * scale * w[tid * 2]) |
                  ((unsigned)f2us(v1 * scale * w[tid * 2 + 1]) << 16);
  *(unsigned*)((ushort*)x + base + tid * 2) = outw;
}

// ================= rmsnorm(x + xa) for the FFN residual =================
__global__ __launch_bounds__(256) void rmsnorm_res_k(
    bf16* __restrict__ x, const float* __restrict__ xa,
    const float* __restrict__ w) {
  int n = blockIdx.x, tid = threadIdx.x;
  long base = (long)n * D_;
  float v0 = b2f(x[base + tid]) + xa[base + tid];
  float v1 = b2f(x[base + tid + 256]) + xa[base + tid + 256];
  float ss = v0 * v0 + v1 * v1;
#pragma unroll
  for (int o = 32; o > 0; o >>= 1) ss += __shfl_xor(ss, o);
  __shared__ float wsum[4];
  if ((tid & 63) == 0) wsum[tid >> 6] = ss;
  __syncthreads();
  float tot = wsum[0] + wsum[1] + wsum[2] + wsum[3];
  float scale = rsqrtf(tot * (1.0f / D_) + EPSF);
  x[base + tid] = f2b(v0 * scale * w[tid]);
  x[base + tid + 256] = f2b(v1 * scale * w[tid + 256]);
}

// ================= bookkeeping =================
__global__ void zero_int_k(int* __restrict__ p) {
  p[blockIdx.x * 256 + threadIdx.x] = 0;
}
__global__ void count_k(const int* __restrict__ key, int* __restrict__ counts) {
  int id = blockIdx.x * 256 + threadIdx.x;
  atomicAdd(&counts[key[id]], 1);
}
__global__ void copy_int_k(const int* __restrict__ in, int* __restrict__ out) {
  int id = blockIdx.x * 256 + threadIdx.x;
  out[id] = in[id];
}
__global__ void fill_csr_k(const int* __restrict__ dst,
                           int* __restrict__ cursor, int* __restrict__ eid) {
  int e = blockIdx.x * 256 + threadIdx.x;
  int pos = atomicAdd(&cursor[dst[e]], 1);
  eid[pos] = e;
}
// exclusive scan over N=65536 ints, single block of 1024 threads
__global__ __launch_bounds__(1024) void scanN_k(const int* __restrict__ cnt,
                                                int* __restrict__ ptr) {
  __shared__ int sums[1024];
  int t = threadIdx.x;
  int base = t * 64;
  int s = 0;
  for (int i = 0; i < 64; ++i) s += cnt[base + i];
  sums[t] = s;
  __syncthreads();
  for (int off = 1; off < 1024; off <<= 1) {
    int v = (t >= off) ? sums[t - off] : 0;
    __syncthreads();
    sums[t] += v;
    __syncthreads();
  }
  int run = (t > 0) ? sums[t - 1] : 0;
  for (int i = 0; i < 64; ++i) {
    ptr[base + i] = run;
    run += cnt[base + i];
  }
  if (t == 1023) ptr[N_] = run;
}
__global__ void scan_k(const int* __restrict__ counts, int* __restrict__ starts) {
  __shared__ int buf[G_];
  int t = threadIdx.x;
  int c = counts[t];
  buf[t] = c;
  __syncthreads();
  for (int off = 1; off < G_; off <<= 1) {
    int v = (t >= off) ? buf[t - off] : 0;
    __syncthreads();
    buf[t] += v;
    __syncthreads();
  }
  starts[t] = buf[t] - c;  // exclusive
}

// ================= attention pooling (z is bf16) =================
__global__ __launch_bounds__(256) void pool_k(
    const bf16* __restrict__ z, const float* __restrict__ avW,
    const float* __restrict__ avb, const int* __restrict__ counts,
    const int* __restrict__ starts, float* __restrict__ hg) {
  int g = blockIdx.x, tid = threadIdx.x;
  int cnt = counts[g], st = starts[g];
  __shared__ float aL[M_];
  int wave = tid >> 6, lane = tid & 63;
  for (int m = wave; m < M_; m += 4) {
    float s = 0.f;
    if (m < cnt) {
      const bf16* row = z + (long)(st + m) * D_;
      for (int c = lane; c < D_; c += 64) s += b2f(row[c]) * avW[c];
    }
#pragma unroll
    for (int o = 32; o > 0; o >>= 1) s += __shfl_xor(s, o);
    if (lane == 0) aL[m] = s;
  }
  __syncthreads();
  if (tid < 64) {
    float v = (tid < cnt) ? aL[tid] + avb[0] : -__builtin_inff();
    float mxv = v;
#pragma unroll
    for (int o = 32; o > 0; o >>= 1) mxv = fmaxf(mxv, __shfl_xor(mxv, o));
    float p = (tid < cnt) ? expf(v - mxv) : 0.f;
    float sm = p;
#pragma unroll
    for (int o = 32; o > 0; o >>= 1) sm += __shfl_xor(sm, o);
    aL[tid] = p / sm;
  }
  __syncthreads();
  for (int d = tid; d < D_; d += 256) {
    float acc = 0.f;
    for (int m = 0; m < cnt; ++m) acc += b2f(z[(long)(st + m) * D_ + d]) * aL[m];
    hg[(long)g * D_ + d] = acc;
  }
}

__global__ __launch_bounds__(256) void rms_relu_k(
    const float* __restrict__ in, const float* __restrict__ w,
    float* __restrict__ out) {
  int g = blockIdx.x, tid = threadIdx.x;
  long base = (long)g * P_;
  float v[4], ss = 0.f;
#pragma unroll
  for (int k = 0; k < 4; ++k) {
    v[k] = in[base + tid + k * 256];
    ss += v[k] * v[k];
  }
#pragma unroll
  for (int o = 32; o > 0; o >>= 1) ss += __shfl_xor(ss, o);
  __shared__ float wsum[4];
  if ((tid & 63) == 0) wsum[tid >> 6] = ss;
  __syncthreads();
  float tot = wsum[0] + wsum[1] + wsum[2] + wsum[3];
  float scale = rsqrtf(tot * (1.0f / P_) + EPSF);
#pragma unroll
  for (int k = 0; k < 4; ++k) {
    float c = v[k] * scale * w[tid + k * 256];
    out[base + tid + k * 256] = fmaxf(c, 0.f);
  }
}

// ================= final outputs =================
__global__ __launch_bounds__(256) void write_dense_k(
    const bf16* __restrict__ x, const int* __restrict__ counts,
    const int* __restrict__ starts, float* __restrict__ out1) {
  long id = (long)blockIdx.x * 256 + threadIdx.x;  // G*M*D
  int g = (int)(id >> 15);
  int rem = (int)(id & 32767);
  int m = rem >> 9, d = rem & 511;
  float v = 0.f;
  if (m < counts[g]) v = b2f(x[(long)(starts[g] + m) * D_ + d]);
  out1[id] = v;
}
__global__ void write_mask_k(const int* __restrict__ counts,
                             float* __restrict__ out2) {
  int id = blockIdx.x * 256 + threadIdx.x;  // G*M
  out2[id] = ((id & 63) < counts[id >> 6]) ? 1.f : 0.f;
}

}  // namespace

extern "C" void kernel_launch(void* const* d_in, const int* in_sizes, int n_in,
                              void* d_out, int out_size, void* d_ws,
                              size_t ws_size, hipStream_t stream) {
  const int* node_x = (const int*)d_in[0];
  const int* edge_attr_idx = (const int*)d_in[1];
  const int* edge_index = (const int*)d_in[2];
  const int* batch = (const int*)d_in[3];
  const float* atom_emb = (const float*)d_in[4];
  const float* edge_emb = (const float*)d_in[5];
  const float* Wl = (const float*)d_in[6];
  const float* bl = (const float*)d_in[7];
  const float* Wr = (const float*)d_in[8];
  const float* br = (const float*)d_in[9];
  const float* We = (const float*)d_in[10];
  const float* att = (const float*)d_in[11];
  const float* gb = (const float*)d_in[12];
  const float* n1w = (const float*)d_in[13];
  const float* f1w = (const float*)d_in[14];
  const float* f1b = (const float*)d_in[15];
  const float* f2w = (const float*)d_in[16];
  const float* f2b = (const float*)d_in[17];
  const float* n2w = (const float*)d_in[18];
  const float* gapW = (const float*)d_in[19];
  const float* gapb = (const float*)d_in[20];
  const float* avW = (const float*)d_in[21];
  const float* avb = (const float*)d_in[22];
  const float* p1W = (const float*)d_in[23];
  const float* p1b = (const float*)d_in[24];
  const float* pnw = (const float*)d_in[25];
  const float* p2W = (const float*)d_in[26];
  const float* p2b = (const float*)d_in[27];
  const int* src = edge_index;
  const int* dst = edge_index + E_;

  // ---- workspace layout ----
  char* ws = (char*)d_ws;
  bf16* x = (bf16*)ws;                                   // N*D bf16
  bf16* xl = x + (long)N_ * D_;                          // N*D bf16
  bf16* xr = xl + (long)N_ * D_;                         // N*D bf16
  bf16* region = xr + (long)N_ * D_;  // 41.9MB region (old eebuf+echunk)
  bf16* ee_tab = region;                                 // TKP*D bf16 = 11MB
  bf16* eattr_tab = ee_tab + (long)TKP * D_;             // TKP*ED bf16 = 2.75MB
  float* logits = (float*)(region + (long)32768 * D_ + (long)32768 * ED_);
  int* keys = (int*)(logits + (long)E_ * H_);            // E ints (old mx)
  float* denom_unused = (float*)(keys + N_ * H_);        // (old denom)
  int* counts = (int*)(denom_unused + (long)N_ * H_);    // G
  int* starts = counts + G_;                             // G
  float* hg = (float*)(starts + G_);                     // G*D fp32
  float* tmpP = hg + (long)G_ * D_;                      // G*P fp32
  float* hp = tmpP + (long)G_ * P_;                      // G*P fp32
  // FFN hidden buffer aliases xl+xr (both dead during FFN phase):
  // NCHUNK*4D bf16 = 32768*2048*2 B = 134.2 MB = |xl| + |xr| exactly.
  bf16* hid = xl;

  // per-layer bf16 transposed weights, aliased on tmpP+hp (dead during layers)
  bf16* wsc = (bf16*)tmpP;  // 8.39 MB available, 5.37 MB used
  bf16* Wl_b = wsc;
  bf16* Wr_b = Wl_b + 512 * 512;
  bf16* We_b = Wr_b + 512 * 512;        // [512][128]
  bf16* f1w_b = We_b + 512 * 128;       // [2048][512]
  bf16* f2w_b = f1w_b + 2048 * 512;     // [512][2048]

  float* out0 = (float*)d_out;                 // [G,P]
  float* out1 = out0 + (long)G_ * P_;          // [G,M,D]
  float* out2 = out1 + (long)G_ * M_ * D_;     // [G,M]
  float* xa = out1;  // FFN residual accumulator aliases out1 (dead at end)

  // dst-CSR lives in out0 (written only at the very end of the launch)
  int* csr_eid = (int*)out0;        // E
  int* csr_ptr = csr_eid + E_;      // N+1
  int* cursor = csr_ptr + N_ + 1;   // N

  encode_nodes_k<<<N_, 256, 0, stream>>>(node_x, atom_emb, x);

  // ---- one-time: edge-type keys + eattr table; dst-CSR ----
  build_keys_k<<<E_ / 256, 256, 0, stream>>>(edge_attr_idx, keys);
  build_eattr_tab_k<<<TKP, 128, 0, stream>>>(edge_emb, eattr_tab);
  zero_int_k<<<N_ / 256, 256, 0, stream>>>(cursor);
  count_k<<<E_ / 256, 256, 0, stream>>>(dst, cursor);
  scanN_k<<<1, 1024, 0, stream>>>(cursor, csr_ptr);
  copy_int_k<<<N_ / 256, 256, 0, stream>>>(csr_ptr, cursor);
  fill_csr_k<<<E_ / 256, 256, 0, stream>>>(dst, cursor, csr_eid);

  for (int l = 0; l < L_; ++l) {
    const float* Wl_l = Wl + (long)l * D_ * D_;
    const float* bl_l = bl + (long)l * D_;
    const float* Wr_l = Wr + (long)l * D_ * D_;
    const float* br_l = br + (long)l * D_;
    const float* We_l = We + (long)l * ED_ * D_;
    const float* att_l = att + (long)l * H_ * C_;
    const float* gb_l = gb + (long)l * D_;
    const float* n1w_l = n1w + (long)l * D_;
    const float* f1w_l = f1w + (long)l * D_ * 4 * D_;
    const float* f1b_l = f1b + (long)l * 4 * D_;
    const float* f2w_l = f2w + (long)l * 4 * D_ * D_;
    const float* f2b_l = f2b + (long)l * D_;
    const float* n2w_l = n2w + (long)l * D_;

    // weights -> bf16 B^T
    transpose_cvt_k<<<dim3(16, 16), dim3(32, 8), 0, stream>>>(Wl_l, Wl_b, 512, 512);
    transpose_cvt_k<<<dim3(16, 16), dim3(32, 8), 0, stream>>>(Wr_l, Wr_b, 512, 512);
    transpose_cvt_k<<<dim3(16, 4), dim3(32, 8), 0, stream>>>(We_l, We_b, 128, 512);
    transpose_cvt_k<<<dim3(64, 16), dim3(32, 8), 0, stream>>>(f1w_l, f1w_b, 512, 2048);
    transpose_cvt_k<<<dim3(16, 64), dim3(32, 8), 0, stream>>>(f2w_l, f2w_b, 2048, 512);

    mfma_gemm_k<0, 1><<<dim3(N_ / 128, D_ / 128), 256, 0, stream>>>(
        (const ushort*)x, (const ushort*)Wl_b, bl_l, xl, N_, D_, D_);
    mfma_gemm_k<0, 1><<<dim3(N_ / 128, D_ / 128), 256, 0, stream>>>(
        (const ushort*)x, (const ushort*)Wr_b, br_l, xr, N_, D_, D_);
    // ee table for this layer: [TKP, D] = eattr_tab @ We
    mfma_gemm_k<0, 1><<<dim3(TKP / 128, D_ / 128), 256, 0, stream>>>(
        (const ushort*)eattr_tab, (const ushort*)We_b, nullptr, ee_tab, TKP,
        ED_, D_);
    edge_logits_k<<<E_ / 4, 256, 0, stream>>>(
        (const ushort*)xl, (const ushort*)xr, (const ushort*)ee_tab, keys,
        att_l, src, dst, logits);
    gat_aggr_norm_k<<<N_, 256, 0, stream>>>(x, xl, logits, csr_ptr, csr_eid,
                                            src, gb_l, n1w_l);

    for (int nc = 0; nc < NCH; ++nc) {
      long nbase = (long)nc * NCHUNK;
      mfma_gemm_k<1, 1><<<dim3(NCHUNK / 128, (4 * D_) / 128), 256, 0, stream>>>(
          (const ushort*)(x + nbase * D_), (const ushort*)f1w_b, f1b_l, hid,
          NCHUNK, D_, 4 * D_);
      mfma_gemm_k<0, 0><<<dim3(NCHUNK / 128, D_ / 128), 256, 0, stream>>>(
          (const ushort*)hid, (const ushort*)f2w_b, f2b_l, xa + nbase * D_,
          NCHUNK, 4 * D_, D_);
    }
    rmsnorm_res_k<<<N_, 256, 0, stream>>>(x, xa, n2w_l);
  }

  // batch bookkeeping
  zero_int_k<<<G_ / 256, 256, 0, stream>>>(counts);
  count_k<<<N_ / 256, 256, 0, stream>>>(batch, counts);
  scan_k<<<1, G_, 0, stream>>>(counts, starts);

  // pooling head: z into xl; gapW bf16^T into eattr_tab slot (free now)
  bf16* gapW_b = eattr_tab;
  transpose_cvt_k<<<dim3(16, 16), dim3(32, 8), 0, stream>>>(gapW, gapW_b, 512, 512);
  mfma_gemm_k<0, 1><<<dim3(N_ / 128, D_ / 128), 256, 0, stream>>>(
      (const ushort*)x, (const ushort*)gapW_b, gapb, xl, N_, D_, D_);
  pool_k<<<G_, 256, 0, stream>>>(xl, avW, avb, counts, starts, hg);
  gemm_bias_k<0, float, float><<<dim3(G_ / 64, P_ / 64), 256, 0, stream>>>(
      hg, p1W, p1b, tmpP, G_, D_, P_);
  rms_relu_k<<<G_, 256, 0, stream>>>(tmpP, pnw, hp);
  gemm_bias_k<0, float, float><<<dim3(G_ / 64, P_ / 64), 256, 0, stream>>>(
      hp, p2W, p2b, out0, G_, P_, P_);

  write_dense_k<<<(int)(((long)G_ * M_ * D_) / 256), 256, 0, stream>>>(
      x, counts, starts, out1);
  write_mask_k<<<(G_ * M_) / 256, 256, 0, stream>>>(counts, out2);
}

// Round 4
// 4117.867 us; speedup vs baseline: 7.7194x; 1.2461x over previous
//
#include <hip/hip_runtime.h>
#include <hip/hip_bf16.h>
#include <math.h>

namespace {

using bf16 = __hip_bfloat16;
typedef __bf16 bf16x8 __attribute__((ext_vector_type(8)));
typedef float f32x4 __attribute__((ext_vector_type(4)));

constexpr int N_ = 65536, E_ = 262144, G_ = 1024, M_ = 64;
constexpr int D_ = 512, H_ = 8, C_ = 64, ED_ = 128, P_ = 1024, L_ = 5;
constexpr float SLOPE = 0.2f;
constexpr float EPSF = 1.1920929e-7f;   // finfo(float32).eps

constexpr int NCH = 2;                  // FFN row chunks (hid aliases xl+xr)
constexpr int NCHUNK = N_ / NCH;        // 32768 rows/chunk

constexpr int TV = 22;                  // edge vocab per slot
constexpr int TK = TV * TV * TV;        // 10648 distinct edge types
constexpr int TKP = 10752;              // padded to %128

constexpr int CH = 4;                   // edges per online-softmax chunk

__device__ inline float b2f(bf16 h) { return __bfloat162float(h); }
__device__ inline bf16 f2b(float f) { return __float2bfloat16(f); }
__device__ inline float us2f(unsigned short u) {
  return __uint_as_float((unsigned)u << 16);
}
__device__ inline unsigned short f2us(float f) {
  bf16 b = __float2bfloat16(f);
  return *(unsigned short*)&b;
}

// ---- async global->LDS, 16B/lane ----
typedef __attribute__((address_space(1))) void as1_void_t;
typedef __attribute__((address_space(3))) void as3_void_t;
__device__ inline void gload16(const void* g, void* l) {
  __builtin_amdgcn_global_load_lds((const as1_void_t*)g, (as3_void_t*)l, 16, 0,
                                   0);
}

// ============== MFMA bf16 GEMM: C[M,Nc] = A[M,K] @ Bt[Nc,K]^T + bias =========
// A row-major bf16, Bt = B^T row-major bf16. 128x128 tile, 4 waves (2x2),
// BK=64, global_load_lds staging with XOR-swizzled SOURCE (slot ^= row&7) so
// the ds_read_b128 fragment reads are bank-conflict-free (G21 both-sides rule).
template <int EPI, int OBF>  // EPI: 0 none, 1 exact gelu; OBF: bf16 out?
__global__ __launch_bounds__(256) void mfma_gemm_k(
    const ushort* __restrict__ A, const ushort* __restrict__ Bt,
    const float* __restrict__ bias, void* __restrict__ Cv, int M, int K,
    int Nc) {
  __shared__ __align__(16) ushort As[128 * 64];  // [row][64], 128B rows
  __shared__ __align__(16) ushort Bs[128 * 64];
  const int tid = threadIdx.x;
  const int wave = tid >> 6, lane = tid & 63;
  const int m0 = blockIdx.x * 128, n0 = blockIdx.y * 128;
  const int wr = wave >> 1, wc = wave & 1;  // 2x2 wave grid, 64x64 each
  const int srow = tid >> 3;
  const int skoff = (((tid & 7) ^ (srow & 7)) << 3);  // inverse-swizzled source
  const ushort* Ap = A + (size_t)(m0 + srow) * K + skoff;
  const ushort* Bp = Bt + (size_t)(n0 + srow) * K + skoff;
  char* AsB = (char*)As + wave * 1024;  // wave-uniform LDS base (+r*4096)
  char* BsB = (char*)Bs + wave * 1024;
  const int fr = lane & 15, fg = lane >> 4;
  const int rx = fr & 7;
  const int sA0 = ((fg) ^ rx) << 3;        // ks=0 slot offset (ushorts)
  const int sA1 = ((4 | fg) ^ rx) << 3;    // ks=1
  const ushort* Arow = As + (wr * 64 + fr) * 64;
  const ushort* Brow = Bs + (wc * 64 + fr) * 64;
  f32x4 acc[4][4];
#pragma unroll
  for (int i = 0; i < 4; ++i)
#pragma unroll
    for (int j = 0; j < 4; ++j) acc[i][j] = (f32x4){0.f, 0.f, 0.f, 0.f};

  for (int kt = 0; kt < K; kt += 64) {
#pragma unroll
    for (int r = 0; r < 4; ++r) {
      gload16(Ap + kt + (size_t)r * 32 * K, AsB + r * 4096);
      gload16(Bp + kt + (size_t)r * 32 * K, BsB + r * 4096);
    }
    __syncthreads();  // compiler drains vmcnt(0) before s_barrier
    bf16x8 af[4], bg[4];
#pragma unroll
    for (int i = 0; i < 4; ++i)
      af[i] = *(const bf16x8*)(Arow + i * 1024 + sA0);
#pragma unroll
    for (int j = 0; j < 4; ++j)
      bg[j] = *(const bf16x8*)(Brow + j * 1024 + sA0);
#pragma unroll
    for (int i = 0; i < 4; ++i)
#pragma unroll
      for (int j = 0; j < 4; ++j)
        acc[i][j] = __builtin_amdgcn_mfma_f32_16x16x32_bf16(af[i], bg[j],
                                                            acc[i][j], 0, 0, 0);
#pragma unroll
    for (int i = 0; i < 4; ++i)
      af[i] = *(const bf16x8*)(Arow + i * 1024 + sA1);
#pragma unroll
    for (int j = 0; j < 4; ++j)
      bg[j] = *(const bf16x8*)(Brow + j * 1024 + sA1);
#pragma unroll
    for (int i = 0; i < 4; ++i)
#pragma unroll
      for (int j = 0; j < 4; ++j)
        acc[i][j] = __builtin_amdgcn_mfma_f32_16x16x32_bf16(af[i], bg[j],
                                                            acc[i][j], 0, 0, 0);
    __syncthreads();
  }
  // epilogue: C/D frag mapping col=lane&15, row=(lane>>4)*4+reg (m89-verified)
  const int cb = n0 + wc * 64 + fr;
  float bv[4];
#pragma unroll
  for (int j = 0; j < 4; ++j) bv[j] = bias ? bias[cb + j * 16] : 0.f;
#pragma unroll
  for (int i = 0; i < 4; ++i) {
#pragma unroll
    for (int r = 0; r < 4; ++r) {
      int m = m0 + wr * 64 + i * 16 + fg * 4 + r;
      size_t rb = (size_t)m * Nc + cb;
#pragma unroll
      for (int j = 0; j < 4; ++j) {
        float c = acc[i][j][r] + bv[j];
        if (EPI == 1) c = 0.5f * c * (1.f + erff(c * 0.70710678118654752f));
        if (OBF)
          ((bf16*)Cv)[rb + j * 16] = f2b(c);
        else
          ((float*)Cv)[rb + j * 16] = c;
      }
    }
  }
}

// ---- one-time per layer: W[K][N] fp32 -> Wt[N][K] bf16 (B^T for the GEMM) ---
__global__ __launch_bounds__(256) void transpose_cvt_k(
    const float* __restrict__ W, bf16* __restrict__ Wt, int K, int N) {
  __shared__ float tile[32][33];
  int bn = blockIdx.x * 32, bk = blockIdx.y * 32;
  int tx = threadIdx.x, ty = threadIdx.y;  // (32,8)
#pragma unroll
  for (int i = ty; i < 32; i += 8) tile[i][tx] = W[(size_t)(bk + i) * N + bn + tx];
  __syncthreads();
#pragma unroll
  for (int i = ty; i < 32; i += 8)
    Wt[(size_t)(bn + i) * K + bk + tx] = f2b(tile[tx][i]);
}

// ========== legacy fp32 SIMT GEMM (kept only for the tiny fp32 head) =========
template <int EPI, typename TIN, typename TOUT>
__global__ __launch_bounds__(256) void gemm_bias_k(
    const TIN* __restrict__ A, const float* __restrict__ B,
    const float* __restrict__ bias, TOUT* __restrict__ C, int M, int K,
    int Nc) {
  __shared__ float As[64][17];
  __shared__ float Bs[16][68];
  const int tid = threadIdx.x;
  const int m0 = blockIdx.x * 64;
  const int n0 = blockIdx.y * 64;
  const int ty = tid >> 4, tx = tid & 15;
  const int lam = tid >> 2;
  const int lak = (tid & 3) << 2;
  const int lbk = tid >> 4;
  const int lbn = (tid & 15) << 2;
  const TIN* Aptr = A + (long)(m0 + lam) * K + lak;
  const float* Bptr = B + (long)lbk * Nc + n0 + lbn;
  float acc[4][4] = {};
  for (int kt = 0; kt < K; kt += 16) {
    float4 va = *(const float4*)(Aptr + kt);
    float4 vb = *(const float4*)(Bptr + (long)kt * Nc);
    __syncthreads();
    As[lam][lak + 0] = va.x; As[lam][lak + 1] = va.y;
    As[lam][lak + 2] = va.z; As[lam][lak + 3] = va.w;
    Bs[lbk][lbn + 0] = vb.x; Bs[lbk][lbn + 1] = vb.y;
    Bs[lbk][lbn + 2] = vb.z; Bs[lbk][lbn + 3] = vb.w;
    __syncthreads();
#pragma unroll
    for (int kk = 0; kk < 16; ++kk) {
      float a[4], b[4];
#pragma unroll
      for (int i = 0; i < 4; ++i) a[i] = As[ty * 4 + i][kk];
#pragma unroll
      for (int j = 0; j < 4; ++j) b[j] = Bs[kk][tx * 4 + j];
#pragma unroll
      for (int i = 0; i < 4; ++i)
#pragma unroll
        for (int j = 0; j < 4; ++j) acc[i][j] = fmaf(a[i], b[j], acc[i][j]);
    }
  }
#pragma unroll
  for (int i = 0; i < 4; ++i) {
    long row = (long)(m0 + ty * 4 + i) * Nc + n0;
#pragma unroll
    for (int j = 0; j < 4; ++j) {
      float c = acc[i][j] + (bias ? bias[n0 + tx * 4 + j] : 0.f);
      if (EPI == 1) c = 0.5f * c * (1.f + erff(c * 0.70710678118654752f));
      ((float*)C)[row + tx * 4 + j] = c;
    }
  }
}

// ================= encoders =================
__global__ __launch_bounds__(256) void encode_nodes_k(
    const int* __restrict__ nodeX, const float* __restrict__ atomEmb,
    bf16* __restrict__ x) {
  int n = blockIdx.x, tid = threadIdx.x;
  __shared__ int idx[9];
  if (tid < 9) idx[tid] = nodeX[n * 9 + tid];
  __syncthreads();
  for (int d = tid; d < D_; d += 256) {
    float s = 0.f;
#pragma unroll
    for (int k = 0; k < 9; ++k) s += atomEmb[(k * 119 + idx[k]) * D_ + d];
    x[(long)n * D_ + d] = f2b(s);
  }
}

// edge-type key per edge: key = i0*TV^2 + i1*TV + i2  (layer-invariant)
__global__ __launch_bounds__(256) void build_keys_k(
    const int* __restrict__ eai, int* __restrict__ keys) {
  int e = blockIdx.x * 256 + threadIdx.x;
  keys[e] = eai[e * 3] * (TV * TV) + eai[e * 3 + 1] * TV + eai[e * 3 + 2];
}

// eattr table: one row per distinct (i0,i1,i2); rows >= TK zeroed (GEMM pad)
__global__ __launch_bounds__(128) void build_eattr_tab_k(
    const float* __restrict__ edgeEmb, bf16* __restrict__ tab) {
  int r = blockIdx.x, d = threadIdx.x;
  float s = 0.f;
  if (r < TK) {
    int k0 = r / (TV * TV), k1 = (r / TV) % TV, k2 = r % TV;
    s = edgeEmb[(0 * TV + k0) * ED_ + d] + edgeEmb[(1 * TV + k1) * ED_ + d] +
        edgeEmb[(2 * TV + k2) * ED_ + d];
  }
  tab[(size_t)r * ED_ + d] = f2b(s);
}

// ===== fully-fused GATv2 layer: logits + segment-softmax + aggregate + gb +
// ===== residual + rmsnorm. ONE WAVE PER NODE, no LDS, no block barriers.
// lane l covers d = l*8..l*8+7 (uint4 = 8 bf16); head = l>>3 (d-range matches).
// Online (flash-style) softmax over in-edge chunks of CH; xl rows cached in
// registers so the aggregation gather re-uses the logit loads.
__global__ __launch_bounds__(256) void gat_fused_k(
    bf16* __restrict__ x, const ushort* __restrict__ xl,
    const ushort* __restrict__ xr, const ushort* __restrict__ ee_tab,
    const int* __restrict__ keys, const float* __restrict__ att,
    const int* __restrict__ ptr, const int* __restrict__ eid,
    const int* __restrict__ src, const float* __restrict__ gb,
    const float* __restrict__ w) {
  const int wave = threadIdx.x >> 6, lane = threadIdx.x & 63;
  const int n = blockIdx.x * 4 + wave;
  const int d0 = lane * 8;
  const int beg = ptr[n], deg = ptr[n + 1] - beg;

  // per-lane att slice (same head for all 8 elems)
  float4 a0 = *(const float4*)(att + d0);
  float4 a1 = *(const float4*)(att + d0 + 4);
  float attv[8] = {a0.x, a0.y, a0.z, a0.w, a1.x, a1.y, a1.z, a1.w};
  // xr[n] row, kept in registers
  uint4 xru = *(const uint4*)(xr + (size_t)n * D_ + d0);
  float xrf[8];
#pragma unroll
  for (int q = 0; q < 4; ++q) {
    unsigned u = (&xru.x)[q];
    xrf[2 * q] = us2f((ushort)u);
    xrf[2 * q + 1] = us2f((ushort)(u >> 16));
  }

  float m = -__builtin_inff(), den = 0.f;
  float acc[8] = {0.f, 0.f, 0.f, 0.f, 0.f, 0.f, 0.f, 0.f};

  for (int c0 = 0; c0 < deg; c0 += CH) {
    int cn = min(deg - c0, CH);
    int s_l = 0, k_l = 0;
    if (lane < cn) {
      int e = eid[beg + c0 + lane];
      s_l = src[e];
      k_l = keys[e];
    }
    uint4 xlv[CH];
    float lg[CH];
#pragma unroll
    for (int i = 0; i < CH; ++i) {
      lg[i] = -__builtin_inff();
      if (i < cn) {
        int s = __shfl(s_l, i);
        int k = __shfl(k_l, i);
        xlv[i] = *(const uint4*)(xl + (size_t)s * D_ + d0);
        uint4 ev = *(const uint4*)(ee_tab + (size_t)k * D_ + d0);
        float part = 0.f;
#pragma unroll
        for (int q = 0; q < 4; ++q) {
          unsigned ua = (&xlv[i].x)[q];
          unsigned ue = (&ev.x)[q];
          float v0 = us2f((ushort)ua) + xrf[2 * q] + us2f((ushort)ue);
          float v1 =
              us2f((ushort)(ua >> 16)) + xrf[2 * q + 1] + us2f((ushort)(ue >> 16));
          v0 = (v0 > 0.f) ? v0 : SLOPE * v0;
          v1 = (v1 > 0.f) ? v1 : SLOPE * v1;
          part = fmaf(v0, attv[2 * q], part);
          part = fmaf(v1, attv[2 * q + 1], part);
        }
        // reduce over the 8-lane head group (lanes l^1, l^2, l^4 same head)
        part += __shfl_xor(part, 1);
        part += __shfl_xor(part, 2);
        part += __shfl_xor(part, 4);
        lg[i] = part;
      }
    }
    // online softmax: rescale running state to the new max
    float cm = lg[0];
#pragma unroll
    for (int i = 1; i < CH; ++i) cm = fmaxf(cm, lg[i]);
    if (cm > m) {
      float sc = expf(m - cm);  // first chunk: exp(-inf)=0 zeroes empty state
      den *= sc;
#pragma unroll
      for (int j = 0; j < 8; ++j) acc[j] *= sc;
      m = cm;
    }
#pragma unroll
    for (int i = 0; i < CH; ++i) {
      if (i < cn) {
        float p = expf(lg[i] - m);
        den += p;
#pragma unroll
        for (int q = 0; q < 4; ++q) {
          unsigned ua = (&xlv[i].x)[q];
          acc[2 * q] = fmaf(us2f((ushort)ua), p, acc[2 * q]);
          acc[2 * q + 1] = fmaf(us2f((ushort)(ua >> 16)), p, acc[2 * q + 1]);
        }
      }
    }
  }

  float inv = (deg > 0) ? 1.f / den : 0.f;
  uint4 xu = *(const uint4*)((const ushort*)x + (size_t)n * D_ + d0);
  float4 g0 = *(const float4*)(gb + d0);
  float4 g1 = *(const float4*)(gb + d0 + 4);
  float gbv[8] = {g0.x, g0.y, g0.z, g0.w, g1.x, g1.y, g1.z, g1.w};
  float v[8], ss = 0.f;
#pragma unroll
  for (int q = 0; q < 4; ++q) {
    unsigned u = (&xu.x)[q];
    v[2 * q] = us2f((ushort)u) + acc[2 * q] * inv + gbv[2 * q];
    v[2 * q + 1] = us2f((ushort)(u >> 16)) + acc[2 * q + 1] * inv + gbv[2 * q + 1];
  }
#pragma unroll
  for (int j = 0; j < 8; ++j) ss += v[j] * v[j];
#pragma unroll
  for (int o = 1; o < 64; o <<= 1) ss += __shfl_xor(ss, o);
  float scale = rsqrtf(ss * (1.0f / D_) + EPSF);
  float4 w0 = *(const float4*)(w + d0);
  float4 w1 = *(const float4*)(w + d0 + 4);
  float wv[8] = {w0.x, w0.y, w0.z, w0.w, w1.x, w1.y, w1.z, w1.w};
  uint4 outv;
#pragma unroll
  for (int q = 0; q < 4; ++q) {
    unsigned lo = f2us(v[2 * q] * scale * wv[2 * q]);
    unsigned hi = f2us(v[2 * q + 1] * scale * wv[2 * q + 1]);
    (&outv.x)[q] = lo | (hi << 16);
  }
  *(uint4*)((ushort*)x + (size_t)n * D_ + d0) = outv;
}

// ================= rmsnorm(x + xa) for the FFN residual =================
__global__ __launch_bounds__(256) void rmsnorm_res_k(
    bf16* __restrict__ x, const float* __restrict__ xa,
    const float* __restrict__ w) {
  int n = blockIdx.x, tid = threadIdx.x;
  long base = (long)n * D_;
  float v0 = b2f(x[base + tid]) + xa[base + tid];
  float v1 = b2f(x[base + tid + 256]) + xa[base + tid + 256];
  float ss = v0 * v0 + v1 * v1;
#pragma unroll
  for (int o = 32; o > 0; o >>= 1) ss += __shfl_xor(ss, o);
  __shared__ float wsum[4];
  if ((tid & 63) == 0) wsum[tid >> 6] = ss;
  __syncthreads();
  float tot = wsum[0] + wsum[1] + wsum[2] + wsum[3];
  float scale = rsqrtf(tot * (1.0f / D_) + EPSF);
  x[base + tid] = f2b(v0 * scale * w[tid]);
  x[base + tid + 256] = f2b(v1 * scale * w[tid + 256]);
}

// ================= bookkeeping =================
__global__ void zero_int_k(int* __restrict__ p) {
  p[blockIdx.x * 256 + threadIdx.x] = 0;
}
__global__ void count_k(const int* __restrict__ key, int* __restrict__ counts) {
  int id = blockIdx.x * 256 + threadIdx.x;
  atomicAdd(&counts[key[id]], 1);
}
__global__ void copy_int_k(const int* __restrict__ in, int* __restrict__ out) {
  int id = blockIdx.x * 256 + threadIdx.x;
  out[id] = in[id];
}
__global__ void fill_csr_k(const int* __restrict__ dst,
                           int* __restrict__ cursor, int* __restrict__ eid) {
  int e = blockIdx.x * 256 + threadIdx.x;
  int pos = atomicAdd(&cursor[dst[e]], 1);
  eid[pos] = e;
}
// exclusive scan over N=65536 ints, single block of 1024 threads
__global__ __launch_bounds__(1024) void scanN_k(const int* __restrict__ cnt,
                                                int* __restrict__ ptr) {
  __shared__ int sums[1024];
  int t = threadIdx.x;
  int base = t * 64;
  int s = 0;
  for (int i = 0; i < 64; ++i) s += cnt[base + i];
  sums[t] = s;
  __syncthreads();
  for (int off = 1; off < 1024; off <<= 1) {
    int v = (t >= off) ? sums[t - off] : 0;
    __syncthreads();
    sums[t] += v;
    __syncthreads();
  }
  int run = (t > 0) ? sums[t - 1] : 0;
  for (int i = 0; i < 64; ++i) {
    ptr[base + i] = run;
    run += cnt[base + i];
  }
  if (t == 1023) ptr[N_] = run;
}
__global__ void scan_k(const int* __restrict__ counts, int* __restrict__ starts) {
  __shared__ int buf[G_];
  int t = threadIdx.x;
  int c = counts[t];
  buf[t] = c;
  __syncthreads();
  for (int off = 1; off < G_; off <<= 1) {
    int v = (t >= off) ? buf[t - off] : 0;
    __syncthreads();
    buf[t] += v;
    __syncthreads();
  }
  starts[t] = buf[t] - c;  // exclusive
}

// ================= attention pooling (z is bf16) =================
__global__ __launch_bounds__(256) void pool_k(
    const bf16* __restrict__ z, const float* __restrict__ avW,
    const float* __restrict__ avb, const int* __restrict__ counts,
    const int* __restrict__ starts, float* __restrict__ hg) {
  int g = blockIdx.x, tid = threadIdx.x;
  int cnt = counts[g], st = starts[g];
  __shared__ float aL[M_];
  int wave = tid >> 6, lane = tid & 63;
  for (int m = wave; m < M_; m += 4) {
    float s = 0.f;
    if (m < cnt) {
      const bf16* row = z + (long)(st + m) * D_;
      for (int c = lane; c < D_; c += 64) s += b2f(row[c]) * avW[c];
    }
#pragma unroll
    for (int o = 32; o > 0; o >>= 1) s += __shfl_xor(s, o);
    if (lane == 0) aL[m] = s;
  }
  __syncthreads();
  if (tid < 64) {
    float v = (tid < cnt) ? aL[tid] + avb[0] : -__builtin_inff();
    float mxv = v;
#pragma unroll
    for (int o = 32; o > 0; o >>= 1) mxv = fmaxf(mxv, __shfl_xor(mxv, o));
    float p = (tid < cnt) ? expf(v - mxv) : 0.f;
    float sm = p;
#pragma unroll
    for (int o = 32; o > 0; o >>= 1) sm += __shfl_xor(sm, o);
    aL[tid] = p / sm;
  }
  __syncthreads();
  for (int d = tid; d < D_; d += 256) {
    float acc = 0.f;
    for (int m = 0; m < cnt; ++m) acc += b2f(z[(long)(st + m) * D_ + d]) * aL[m];
    hg[(long)g * D_ + d] = acc;
  }
}

__global__ __launch_bounds__(256) void rms_relu_k(
    const float* __restrict__ in, const float* __restrict__ w,
    float* __restrict__ out) {
  int g = blockIdx.x, tid = threadIdx.x;
  long base = (long)g * P_;
  float v[4], ss = 0.f;
#pragma unroll
  for (int k = 0; k < 4; ++k) {
    v[k] = in[base + tid + k * 256];
    ss += v[k] * v[k];
  }
#pragma unroll
  for (int o = 32; o > 0; o >>= 1) ss += __shfl_xor(ss, o);
  __shared__ float wsum[4];
  if ((tid & 63) == 0) wsum[tid >> 6] = ss;
  __syncthreads();
  float tot = wsum[0] + wsum[1] + wsum[2] + wsum[3];
  float scale = rsqrtf(tot * (1.0f / P_) + EPSF);
#pragma unroll
  for (int k = 0; k < 4; ++k) {
    float c = v[k] * scale * w[tid + k * 256];
    out[base + tid + k * 256] = fmaxf(c, 0.f);
  }
}

// ================= final outputs =================
__global__ __launch_bounds__(256) void write_dense_k(
    const bf16* __restrict__ x, const int* __restrict__ counts,
    const int* __restrict__ starts, float* __restrict__ out1) {
  long id = (long)blockIdx.x * 256 + threadIdx.x;  // G*M*D
  int g = (int)(id >> 15);
  int rem = (int)(id & 32767);
  int m = rem >> 9, d = rem & 511;
  float v = 0.f;
  if (m < counts[g]) v = b2f(x[(long)(starts[g] + m) * D_ + d]);
  out1[id] = v;
}
__global__ void write_mask_k(const int* __restrict__ counts,
                             float* __restrict__ out2) {
  int id = blockIdx.x * 256 + threadIdx.x;  // G*M
  out2[id] = ((id & 63) < counts[id >> 6]) ? 1.f : 0.f;
}

}  // namespace

extern "C" void kernel_launch(void* const* d_in, const int* in_sizes, int n_in,
                              void* d_out, int out_size, void* d_ws,
                              size_t ws_size, hipStream_t stream) {
  const int* node_x = (const int*)d_in[0];
  const int* edge_attr_idx = (const int*)d_in[1];
  const int* edge_index = (const int*)d_in[2];
  const int* batch = (const int*)d_in[3];
  const float* atom_emb = (const float*)d_in[4];
  const float* edge_emb = (const float*)d_in[5];
  const float* Wl = (const float*)d_in[6];
  const float* bl = (const float*)d_in[7];
  const float* Wr = (const float*)d_in[8];
  const float* br = (const float*)d_in[9];
  const float* We = (const float*)d_in[10];
  const float* att = (const float*)d_in[11];
  const float* gb = (const float*)d_in[12];
  const float* n1w = (const float*)d_in[13];
  const float* f1w = (const float*)d_in[14];
  const float* f1b = (const float*)d_in[15];
  const float* f2w = (const float*)d_in[16];
  const float* f2b = (const float*)d_in[17];
  const float* n2w = (const float*)d_in[18];
  const float* gapW = (const float*)d_in[19];
  const float* gapb = (const float*)d_in[20];
  const float* avW = (const float*)d_in[21];
  const float* avb = (const float*)d_in[22];
  const float* p1W = (const float*)d_in[23];
  const float* p1b = (const float*)d_in[24];
  const float* pnw = (const float*)d_in[25];
  const float* p2W = (const float*)d_in[26];
  const float* p2b = (const float*)d_in[27];
  const int* src = edge_index;
  const int* dst = edge_index + E_;

  // ---- workspace layout ----
  char* ws = (char*)d_ws;
  bf16* x = (bf16*)ws;                                   // N*D bf16
  bf16* xl = x + (long)N_ * D_;                          // N*D bf16
  bf16* xr = xl + (long)N_ * D_;                         // N*D bf16
  bf16* region = xr + (long)N_ * D_;  // 41.9MB region
  bf16* ee_tab = region;                                 // TKP*D bf16 = 11MB
  bf16* eattr_tab = ee_tab + (long)TKP * D_;             // TKP*ED bf16 = 2.75MB
  float* logits_unused = (float*)(region + (long)32768 * D_ + (long)32768 * ED_);
  int* keys = (int*)(logits_unused + (long)E_ * H_);     // E ints
  float* denom_unused = (float*)(keys + N_ * H_);
  int* counts = (int*)(denom_unused + (long)N_ * H_);    // G
  int* starts = counts + G_;                             // G
  float* hg = (float*)(starts + G_);                     // G*D fp32
  float* tmpP = hg + (long)G_ * D_;                      // G*P fp32
  float* hp = tmpP + (long)G_ * P_;                      // G*P fp32
  // FFN hidden buffer aliases xl+xr (both dead during FFN phase):
  bf16* hid = xl;

  // per-layer bf16 transposed weights, aliased on tmpP+hp (dead during layers)
  bf16* wsc = (bf16*)tmpP;  // 8.39 MB available, 5.37 MB used
  bf16* Wl_b = wsc;
  bf16* Wr_b = Wl_b + 512 * 512;
  bf16* We_b = Wr_b + 512 * 512;        // [512][128]
  bf16* f1w_b = We_b + 512 * 128;       // [2048][512]
  bf16* f2w_b = f1w_b + 2048 * 512;     // [512][2048]

  float* out0 = (float*)d_out;                 // [G,P]
  float* out1 = out0 + (long)G_ * P_;          // [G,M,D]
  float* out2 = out1 + (long)G_ * M_ * D_;     // [G,M]
  float* xa = out1;  // FFN residual accumulator aliases out1 (dead at end)

  // dst-CSR lives in out0 (written only at the very end of the launch)
  int* csr_eid = (int*)out0;        // E
  int* csr_ptr = csr_eid + E_;      // N+1
  int* cursor = csr_ptr + N_ + 1;   // N

  encode_nodes_k<<<N_, 256, 0, stream>>>(node_x, atom_emb, x);

  // ---- one-time: edge-type keys + eattr table; dst-CSR ----
  build_keys_k<<<E_ / 256, 256, 0, stream>>>(edge_attr_idx, keys);
  build_eattr_tab_k<<<TKP, 128, 0, stream>>>(edge_emb, eattr_tab);
  zero_int_k<<<N_ / 256, 256, 0, stream>>>(cursor);
  count_k<<<E_ / 256, 256, 0, stream>>>(dst, cursor);
  scanN_k<<<1, 1024, 0, stream>>>(cursor, csr_ptr);
  copy_int_k<<<N_ / 256, 256, 0, stream>>>(csr_ptr, cursor);
  fill_csr_k<<<E_ / 256, 256, 0, stream>>>(dst, cursor, csr_eid);

  for (int l = 0; l < L_; ++l) {
    const float* Wl_l = Wl + (long)l * D_ * D_;
    const float* bl_l = bl + (long)l * D_;
    const float* Wr_l = Wr + (long)l * D_ * D_;
    const float* br_l = br + (long)l * D_;
    const float* We_l = We + (long)l * ED_ * D_;
    const float* att_l = att + (long)l * H_ * C_;
    const float* gb_l = gb + (long)l * D_;
    const float* n1w_l = n1w + (long)l * D_;
    const float* f1w_l = f1w + (long)l * D_ * 4 * D_;
    const float* f1b_l = f1b + (long)l * 4 * D_;
    const float* f2w_l = f2w + (long)l * 4 * D_ * D_;
    const float* f2b_l = f2b + (long)l * D_;
    const float* n2w_l = n2w + (long)l * D_;

    // weights -> bf16 B^T
    transpose_cvt_k<<<dim3(16, 16), dim3(32, 8), 0, stream>>>(Wl_l, Wl_b, 512, 512);
    transpose_cvt_k<<<dim3(16, 16), dim3(32, 8), 0, stream>>>(Wr_l, Wr_b, 512, 512);
    transpose_cvt_k<<<dim3(16, 4), dim3(32, 8), 0, stream>>>(We_l, We_b, 128, 512);
    transpose_cvt_k<<<dim3(64, 16), dim3(32, 8), 0, stream>>>(f1w_l, f1w_b, 512, 2048);
    transpose_cvt_k<<<dim3(16, 64), dim3(32, 8), 0, stream>>>(f2w_l, f2w_b, 2048, 512);

    mfma_gemm_k<0, 1><<<dim3(N_ / 128, D_ / 128), 256, 0, stream>>>(
        (const ushort*)x, (const ushort*)Wl_b, bl_l, xl, N_, D_, D_);
    mfma_gemm_k<0, 1><<<dim3(N_ / 128, D_ / 128), 256, 0, stream>>>(
        (const ushort*)x, (const ushort*)Wr_b, br_l, xr, N_, D_, D_);
    // ee table for this layer: [TKP, D] = eattr_tab @ We
    mfma_gemm_k<0, 1><<<dim3(TKP / 128, D_ / 128), 256, 0, stream>>>(
        (const ushort*)eattr_tab, (const ushort*)We_b, nullptr, ee_tab, TKP,
        ED_, D_);

    gat_fused_k<<<N_ / 4, 256, 0, stream>>>(
        x, (const ushort*)xl, (const ushort*)xr, (const ushort*)ee_tab, keys,
        att_l, csr_ptr, csr_eid, src, gb_l, n1w_l);

    for (int nc = 0; nc < NCH; ++nc) {
      long nbase = (long)nc * NCHUNK;
      mfma_gemm_k<1, 1><<<dim3(NCHUNK / 128, (4 * D_) / 128), 256, 0, stream>>>(
          (const ushort*)(x + nbase * D_), (const ushort*)f1w_b, f1b_l, hid,
          NCHUNK, D_, 4 * D_);
      mfma_gemm_k<0, 0><<<dim3(NCHUNK / 128, D_ / 128), 256, 0, stream>>>(
          (const ushort*)hid, (const ushort*)f2w_b, f2b_l, xa + nbase * D_,
          NCHUNK, 4 * D_, D_);
    }
    rmsnorm_res_k<<<N_, 256, 0, stream>>>(x, xa, n2w_l);
  }

  // batch bookkeeping
  zero_int_k<<<G_ / 256, 256, 0, stream>>>(counts);
  count_k<<<N_ / 256, 256, 0, stream>>>(batch, counts);
  scan_k<<<1, G_, 0, stream>>>(counts, starts);

  // pooling head: z into xl; gapW bf16^T into eattr_tab slot (free now)
  bf16* gapW_b = eattr_tab;
  transpose_cvt_k<<<dim3(16, 16), dim3(32, 8), 0, stream>>>(gapW, gapW_b, 512, 512);
  mfma_gemm_k<0, 1><<<dim3(N_ / 128, D_ / 128), 256, 0, stream>>>(
      (const ushort*)x, (const ushort*)gapW_b, gapb, xl, N_, D_, D_);
  pool_k<<<G_, 256, 0, stream>>>(xl, avW, avb, counts, starts, hg);
  gemm_bias_k<0, float, float><<<dim3(G_ / 64, P_ / 64), 256, 0, stream>>>(
      hg, p1W, p1b, tmpP, G_, D_, P_);
  rms_relu_k<<<G_, 256, 0, stream>>>(tmpP, pnw, hp);
  gemm_bias_k<0, float, float><<<dim3(G_ / 64, P_ / 64), 256, 0, stream>>>(
      hp, p2W, p2b, out0, G_, P_, P_);

  write_dense_k<<<(int)(((long)G_ * M_ * D_) / 256), 256, 0, stream>>>(
      x, counts, starts, out1);
  write_mask_k<<<(G_ * M_) / 256, 256, 0, stream>>>(counts, out2);
}